// Round 18
// baseline (523.259 us; speedup 1.0000x reference)
//
#include <hip/hip_runtime.h>

typedef _Float16 half_t;
typedef _Float16 half2v __attribute__((ext_vector_type(2)));
typedef _Float16 half4v __attribute__((ext_vector_type(4)));
typedef _Float16 half8v __attribute__((ext_vector_type(8)));
typedef float    float4v __attribute__((ext_vector_type(4)));
typedef short    short8v __attribute__((ext_vector_type(8)));

#define S_IMG 2048
#define S_TXT 512
#define S_TOT 2560
#define NH    24
#define HD    128
#define DM    3072
#define WSZC  9437184L   // DM*DM
#define HSZC  6291456L   // S_IMG*DM
#define ESZC  1572864L   // S_TXT*DM

// async global->LDS, 16B per lane, wave-uniform LDS base (+ lane*16 by HW)
__device__ __forceinline__ void gload16(const void* g, void* l) {
  __builtin_amdgcn_global_load_lds(
      (const __attribute__((address_space(1))) unsigned int*)g,
      (__attribute__((address_space(3))) unsigned int*)l, 16, 0, 0);
}

__device__ __forceinline__ void cvt8span(const float* s, half_t* d, long i) {
  float4v v0 = *(const float4v*)(s + i);
  float4v v1 = *(const float4v*)(s + i + 4);
  half8v h;
  h[0] = (half_t)v0[0]; h[1] = (half_t)v0[1]; h[2] = (half_t)v0[2]; h[3] = (half_t)v0[3];
  h[4] = (half_t)v1[0]; h[5] = (half_t)v1[1]; h[6] = (half_t)v1[2]; h[7] = (half_t)v1[3];
  *(half8v*)(d + i) = h;
}

// ---------------------------------------------------------------- activations -> f16 (merged)
__global__ void cvt_act_kernel(const float* __restrict__ hs, const float* __restrict__ enc,
                               half_t* __restrict__ d) {
  const long TOT = HSZC + ESZC;
  long i = ((long)blockIdx.x * 256 + threadIdx.x) * 8;
  long stride = (long)gridDim.x * 256 * 8;
  for (; i < TOT; i += stride) {
    const float* s = i < HSZC ? hs + i : enc + (i - HSZC);
    cvt8span(s, d + i, 0);
  }
}

// ------------------------------------------------ 128x128 GEMM tile, f32 B staged directly
// 2-buffer 1-ahead pipeline. A (f16): 64B rows, XOR slot^=(row>>1)&3. B (f32): 128B rows,
// XOR byte^=(row&7)<<4 (pre-swizzled source, linear LDS dest, swizzled read; 2-way = free).
// In-register f32->f16 convert feeding the MFMA B fragments.
__device__ __forceinline__ void gemm_tile_wf32(half_t* As, char* Bsc,
                                               const half_t* __restrict__ A,
                                               const float* __restrict__ Btf,
                                               const float* __restrict__ bias,
                                               half_t* __restrict__ C, int bm, int bn) {
  const int K = DM, N = DM;
  const int tid = threadIdx.x, wid = tid >> 6, l = tid & 63;
  const int wm = (wid >> 1) * 64, wn = (wid & 1) * 64;
  const int l15 = l & 15, l4 = l >> 4;
  float4v acc[4][4] = {};

  const int scolA = ((l & 3) ^ ((l >> 3) & 3)) * 8;
  const half_t* ga = A + (long)(bm + wid * 32 + (l >> 2)) * K + scolA;
  const long rowstepA = 16l * K;
  // B staging: issue c covers rows c*32 + (tid>>3); swizzled byte-in-row is c-independent
  const int sbyteB = ((tid & 7) * 16) ^ (((tid >> 3) & 7) << 4);
  const float* gb = Btf + (long)(bn + (tid >> 3)) * K + (sbyteB >> 2);
  const long rowstepB = 32l * K;

#define GSTAGE(T, SEL)                                                        \
  {                                                                           \
    char* a_d = (char*)As + (SEL) * 8192 + wid * 2048;                        \
    char* b_d = Bsc + (SEL) * 16384 + wid * 1024;                             \
    int k0 = (T) * 32;                                                        \
    gload16(ga + k0, a_d);                                                    \
    gload16(ga + rowstepA + k0, a_d + 1024);                                  \
    _Pragma("unroll") for (int c = 0; c < 4; c++)                             \
      gload16(gb + c * rowstepB + k0, b_d + c * 4096);                        \
  }

  GSTAGE(0, 0);

  const int NT = K / 32;  // 96
  const int cofsA = (l4 * 16) ^ (((l15 >> 1) & 3) << 4);
  int sel = 0;
  for (int t = 0; t < NT; t++) {
    asm volatile("s_waitcnt vmcnt(0)" ::: "memory");
    __builtin_amdgcn_s_barrier();
    __builtin_amdgcn_sched_barrier(0);
    if (t + 1 < NT) GSTAGE(t + 1, sel ^ 1);
    __builtin_amdgcn_sched_barrier(0);
    const char* AsB = (const char*)As + sel * 8192;
    const char* BsB = Bsc + sel * 16384;
    half8v af[4], bf[4];
#pragma unroll
    for (int i = 0; i < 4; i++)
      af[i] = *(const half8v*)(AsB + (wm + i * 16 + l15) * 64 + cofsA);
#pragma unroll
    for (int j = 0; j < 4; j++) {
      int row = wn + j * 16 + l15;
      int sw = (row & 7) << 4;
      float4v b0 = *(const float4v*)(BsB + (row << 7) + ((l4 * 32) ^ sw));
      float4v b1 = *(const float4v*)(BsB + (row << 7) + ((l4 * 32 + 16) ^ sw));
      half8v hb;
      hb[0] = (half_t)b0[0]; hb[1] = (half_t)b0[1]; hb[2] = (half_t)b0[2]; hb[3] = (half_t)b0[3];
      hb[4] = (half_t)b1[0]; hb[5] = (half_t)b1[1]; hb[6] = (half_t)b1[2]; hb[7] = (half_t)b1[3];
      bf[j] = hb;
    }
    __builtin_amdgcn_s_setprio(1);
#pragma unroll
    for (int i = 0; i < 4; i++)
#pragma unroll
      for (int j = 0; j < 4; j++)
        acc[i][j] = __builtin_amdgcn_mfma_f32_16x16x32_f16(af[i], bf[j], acc[i][j], 0, 0, 0);
    __builtin_amdgcn_s_setprio(0);
    sel ^= 1;
  }
#undef GSTAGE
#pragma unroll
  for (int i = 0; i < 4; i++)
#pragma unroll
    for (int j = 0; j < 4; j++) {
      int row = bm + wm + i * 16 + l4 * 4;
      int col = bn + wn + j * 16 + l15;
      float bv = bias[col];
#pragma unroll
      for (int r = 0; r < 4; r++) {
        float v = acc[i][j][r] + bv;
        C[(long)(row + r) * N + col] = (half_t)v;
      }
    }
}

// ------------------------------------------------ 128x128 GEMM tile body, f16 B (round-16)
template <typename OUT>
__device__ __forceinline__ void gemm_tile(half_t* As, half_t* Bs,  // each 2*4096 halves
                                          const half_t* __restrict__ A,
                                          const half_t* __restrict__ Bt,
                                          const float* __restrict__ bias,
                                          OUT* __restrict__ C, int bm, int bn) {
  const int K = DM, N = DM;
  const int tid = threadIdx.x, wid = tid >> 6, l = tid & 63;
  const int wm = (wid >> 1) * 64, wn = (wid & 1) * 64;
  const int l15 = l & 15, l4 = l >> 4;
  float4v acc[4][4] = {};

  const int scol = ((l & 3) ^ ((l >> 3) & 3)) * 8;
  const half_t* ga = A + (long)(bm + wid * 32 + (l >> 2)) * K + scol;
  const half_t* gb = Bt + (long)(bn + wid * 32 + (l >> 2)) * K + scol;
  const long rowstep = 16l * K;

#define GSTAGE(T, SEL)                                                        \
  {                                                                           \
    char* a_d = (char*)As + (SEL) * 8192 + wid * 2048;                        \
    char* b_d = (char*)Bs + (SEL) * 8192 + wid * 2048;                        \
    int k0 = (T) * 32;                                                        \
    gload16(ga + k0, a_d);                                                    \
    gload16(ga + rowstep + k0, a_d + 1024);                                   \
    gload16(gb + k0, b_d);                                                    \
    gload16(gb + rowstep + k0, b_d + 1024);                                   \
  }

  GSTAGE(0, 0);

  const int NT = K / 32;  // 96
  const int cofs = (l4 * 16) ^ (((l15 >> 1) & 3) << 4);
  int sel = 0;
  for (int t = 0; t < NT; t++) {
    asm volatile("s_waitcnt vmcnt(0)" ::: "memory");
    __builtin_amdgcn_s_barrier();
    __builtin_amdgcn_sched_barrier(0);
    if (t + 1 < NT) GSTAGE(t + 1, sel ^ 1);
    __builtin_amdgcn_sched_barrier(0);
    const char* AsB = (const char*)As + sel * 8192;
    const char* BsB = (const char*)Bs + sel * 8192;
    half8v af[4], bf[4];
#pragma unroll
    for (int i = 0; i < 4; i++)
      af[i] = *(const half8v*)(AsB + (wm + i * 16 + l15) * 64 + cofs);
#pragma unroll
    for (int j = 0; j < 4; j++)
      bf[j] = *(const half8v*)(BsB + (wn + j * 16 + l15) * 64 + cofs);
    __builtin_amdgcn_s_setprio(1);
#pragma unroll
    for (int i = 0; i < 4; i++)
#pragma unroll
      for (int j = 0; j < 4; j++)
        acc[i][j] = __builtin_amdgcn_mfma_f32_16x16x32_f16(af[i], bf[j], acc[i][j], 0, 0, 0);
    __builtin_amdgcn_s_setprio(0);
    sel ^= 1;
  }
#undef GSTAGE
#pragma unroll
  for (int i = 0; i < 4; i++)
#pragma unroll
    for (int j = 0; j < 4; j++) {
      int row = bm + wm + i * 16 + l4 * 4;
      int col = bn + wn + j * 16 + l15;
      float bv = bias ? bias[col] : 0.0f;
#pragma unroll
      for (int r = 0; r < 4; r++) {
        float v = acc[i][j][r] + bv;
        C[(long)(row + r) * N + col] = (OUT)v;
      }
    }
}

// merged img+enc QKV GEMM with f32-direct weights: 1440 blocks, XCD swizzle (8x180)
__global__ __launch_bounds__(256) void gemm_qkv_kernel(
    const half_t* __restrict__ hs_h, const half_t* __restrict__ enc_h,
    const float* Wq, const float* Wk, const float* Wv,
    const float* Waq, const float* Wak, const float* Wav,
    const float* bq, const float* bk, const float* bv,
    const float* baq, const float* bak, const float* bav,
    half_t* q_raw, half_t* k_raw, half_t* v_raw,
    half_t* eq_r, half_t* ek_r, half_t* ev_r) {
  __shared__ half_t As[2 * 4096];
  __shared__ char   Bsc[2 * 16384];
  int b = blockIdx.x;
  int wg = (b & 7) * 180 + (b >> 3);
  const half_t* A;
  const float* Bt;
  const float* bias;
  half_t* C;
  int bm, bn;
  if (wg < 1152) {
    int col = wg / 16, row = wg % 16;
    int sel = col / 24;
    A = hs_h; bm = row * 128; bn = (col % 24) * 128;
    Bt = sel == 0 ? Wq : (sel == 1 ? Wk : Wv);
    bias = sel == 0 ? bq : (sel == 1 ? bk : bv);
    C = sel == 0 ? q_raw : (sel == 1 ? k_raw : v_raw);
  } else {
    int w2 = wg - 1152;
    int col = w2 / 4, row = w2 % 4;
    int sel = col / 24;
    A = enc_h; bm = row * 128; bn = (col % 24) * 128;
    Bt = sel == 0 ? Waq : (sel == 1 ? Wak : Wav);
    bias = sel == 0 ? baq : (sel == 1 ? bak : bav);
    C = sel == 0 ? eq_r : (sel == 1 ? ek_r : ev_r);
  }
  gemm_tile_wf32(As, Bsc, A, Bt, bias, C, bm, bn);
}

// fused output projections; 1D grid 480 = 8 x 60; r<16 img, r>=16 enc (f16 weights)
__global__ __launch_bounds__(256) void gemm_out_kernel(const half_t* __restrict__ ocomb,
                                                       const half_t* __restrict__ Wo_h,
                                                       const half_t* __restrict__ Wao_h,
                                                       const float* bo, const float* bao,
                                                       float* out_img, float* out_enc) {
  __shared__ half_t As[2 * 4096];
  __shared__ half_t Bs[2 * 4096];
  int b = blockIdx.x;
  int wg = (b & 7) * 60 + (b >> 3);
  int col = wg / 20, r = wg % 20;
  bool enc = r >= 16;
  const half_t* A = enc ? ocomb : ocomb + (long)S_TXT * DM;
  int bm = (enc ? (r - 16) : r) * 128;
  gemm_tile<float>(As, Bs, A, enc ? Wao_h : Wo_h, enc ? bao : bo,
                   enc ? out_enc : out_img, bm, col * 128);
}

// ------------------------------------------------ ip projections (M=4, f32 direct), merged k/v
__global__ __launch_bounds__(256) void ip_proj_kernel(const float* __restrict__ x,
                                                      const float* __restrict__ Wk_ip,
                                                      const float* __restrict__ Wv_ip,
                                                      float* __restrict__ outk,
                                                      float* __restrict__ outv) {
  const float* W = blockIdx.y ? Wv_ip : Wk_ip;
  float* out = blockIdx.y ? outv : outk;
  int n = blockIdx.x * 4 + (threadIdx.x >> 6);
  int l = threadIdx.x & 63;
  const float* wr = W + (long)n * DM;
  float acc[4] = {0.f, 0.f, 0.f, 0.f};
  for (int k = l * 4; k < DM; k += 256) {
    float4v wv = *(const float4v*)(wr + k);
#pragma unroll
    for (int p = 0; p < 4; p++) {
      float4v xv = *(const float4v*)(x + p * DM + k);
      acc[p] += wv[0] * xv[0] + wv[1] * xv[1] + wv[2] * xv[2] + wv[3] * xv[3];
    }
  }
#pragma unroll
  for (int off = 32; off; off >>= 1)
#pragma unroll
    for (int p = 0; p < 4; p++) acc[p] += __shfl_xor(acc[p], off, 64);
  if (l == 0)
#pragma unroll
    for (int p = 0; p < 4; p++) out[p * DM + n] = acc[p];
}

// ------------------------------------------------ ip k-norm (eps 1e-5) + v convert
__global__ void ip_norm_kernel(const float* __restrict__ kr, const float* __restrict__ vr,
                               half_t* __restrict__ kh, half_t* __restrict__ vh) {
  int t = blockIdx.x;
  int l = threadIdx.x;
  int d = l * 2;
  if (t < 96) {
    int base = (t / 24) * DM + (t % 24) * HD;
    float x0 = kr[base + d], x1 = kr[base + d + 1];
    float ss = x0 * x0 + x1 * x1;
#pragma unroll
    for (int off = 32; off; off >>= 1) ss += __shfl_xor(ss, off, 64);
    float r = rsqrtf(ss * (1.0f / HD) + 1e-5f);
    kh[base + d] = (half_t)(x0 * r);
    kh[base + d + 1] = (half_t)(x1 * r);
  } else {
    int t2 = t - 96;
    int base = (t2 / 24) * DM + (t2 % 24) * HD;
    vh[base + d] = (half_t)vr[base + d];
    vh[base + d + 1] = (half_t)vr[base + d + 1];
  }
}

// ------------------------------------------------ merged prep (rmsnorm+rope+concat) + vtrans
__global__ __launch_bounds__(256) void prep_vtrans_kernel(
    const half_t* __restrict__ qraw, const half_t* __restrict__ kraw,
    const half_t* __restrict__ eq, const half_t* __restrict__ ek,
    const half_t* __restrict__ ev, const half_t* __restrict__ vraw,
    const float* __restrict__ nqw, const float* __restrict__ nkw,
    const float* __restrict__ naqw, const float* __restrict__ nakw,
    const float* __restrict__ cosb, const float* __restrict__ sinb,
    half_t* __restrict__ qcat, half_t* __restrict__ kcat, half_t* __restrict__ qnr,
    half_t* __restrict__ vcatT) {
  __shared__ half_t T[64][136];
  if (blockIdx.x < 15360) {
    int task = blockIdx.x * 4 + (threadIdx.x >> 6);
    int l = threadIdx.x & 63;
    int s = task / NH, h = task - (task / NH) * NH;
    int d = l * 2;
    const half_t *qs, *ks;
    const float *wq, *wk;
    if (s < S_TXT) {
      long base = (long)s * DM + h * HD;
      qs = eq + base; ks = ek + base;
      wq = naqw; wk = nakw;
    } else {
      long base = (long)(s - S_TXT) * DM + h * HD;
      qs = qraw + base; ks = kraw + base;
      wq = nqw; wk = nkw;
    }
    half2v qv = *(const half2v*)(qs + d);
    half2v kv = *(const half2v*)(ks + d);
    float q0 = (float)qv[0], q1 = (float)qv[1];
    float k0 = (float)kv[0], k1 = (float)kv[1];
    float ssq = q0 * q0 + q1 * q1;
    float ssk = k0 * k0 + k1 * k1;
#pragma unroll
    for (int off = 32; off; off >>= 1) {
      ssq += __shfl_xor(ssq, off, 64);
      ssk += __shfl_xor(ssk, off, 64);
    }
    float rq = rsqrtf(ssq * (1.0f / HD) + 1e-6f);
    float rk = rsqrtf(ssk * (1.0f / HD) + 1e-6f);
    float qn0 = q0 * rq * wq[d], qn1 = q1 * rq * wq[d + 1];
    float kn0 = k0 * rk * wk[d], kn1 = k1 * rk * wk[d + 1];
    if (s >= S_TXT) {
      half2v o; o[0] = (half_t)qn0; o[1] = (half_t)qn1;
      *(half2v*)(qnr + ((long)h * S_IMG + (s - S_TXT)) * HD + d) = o;
    }
    float c0 = cosb[s * HD + d], c1 = cosb[s * HD + d + 1];
    float s0 = sinb[s * HD + d], s1 = sinb[s * HD + d + 1];
    float qo0 = qn0 * c0 - qn1 * s0, qo1 = qn1 * c1 + qn0 * s1;
    float ko0 = kn0 * c0 - kn1 * s0, ko1 = kn1 * c1 + kn0 * s1;
    long ci = ((long)h * S_TOT + s) * HD + d;
    half2v oq; oq[0] = (half_t)qo0; oq[1] = (half_t)qo1;
    half2v ok; ok[0] = (half_t)ko0; ok[1] = (half_t)ko1;
    *(half2v*)(qcat + ci) = oq;
    *(half2v*)(kcat + ci) = ok;
  } else {
    int b2 = blockIdx.x - 15360;       // 960 tiles = 24 heads x 40 s-blocks
    int h = b2 / 40, sb = (b2 % 40) * 64;
    int t = threadIdx.x;
#pragma unroll
    for (int i = 0; i < 4; i++) {
      int c = t + i * 256;
      int row = c >> 4, col = (c & 15) * 8;
      int s = sb + row;
      const half_t* src = (s < S_TXT) ? ev + (long)s * DM + h * HD + col
                                      : vraw + (long)(s - S_TXT) * DM + h * HD + col;
      *(half8v*)&T[row][col] = *(const half8v*)src;
    }
    __syncthreads();
#pragma unroll
    for (int i = 0; i < 4; i++) {
      int c = t + i * 256;
      int d = c >> 3, sc = (c & 7) * 8;
      half8v v;
#pragma unroll
      for (int j = 0; j < 8; j++) v[j] = T[sc + j][d];
      // pi^{-1}: dst_b4 = s_b3, dst_b3 = s_b2, dst_b2 = s_b4 (3-cycle)
      int base = (sc & 32) | ((sc & 8) << 1) | ((sc & 16) >> 2);
      half_t* dst = vcatT + ((long)h * HD + d) * S_TOT + sb;
      half4v q0; q0[0] = v[0]; q0[1] = v[1]; q0[2] = v[2]; q0[3] = v[3];
      half4v q1; q1[0] = v[4]; q1[1] = v[5]; q1[2] = v[6]; q1[3] = v[7];
      *(half4v*)(dst + base) = q0;
      *(half4v*)(dst + base + 8) = q1;
    }
  }
}

// ------------------------------------------------ ip attention (4 keys), 8 halves/lane
__global__ __launch_bounds__(256) void ip_attn_kernel(const half_t* __restrict__ qnr,
                                                      const half_t* __restrict__ kh,
                                                      const half_t* __restrict__ vh,
                                                      half_t* __restrict__ ipout) {
  int tid = threadIdx.x;
  int task = blockIdx.x * 16 + (tid >> 4);
  int l16 = tid & 15;
  int h = task >> 11;
  int s = task & 2047;
  int d = l16 * 8;
  half8v qv = *(const half8v*)(qnr + ((long)h * S_IMG + s) * HD + d);
  float sc[4];
#pragma unroll
  for (int p = 0; p < 4; p++) {
    half8v kv = *(const half8v*)(kh + p * DM + h * HD + d);
    float a = 0.f;
#pragma unroll
    for (int j = 0; j < 8; j++) a += (float)qv[j] * (float)kv[j];
    sc[p] = a;
  }
#pragma unroll
  for (int off = 8; off; off >>= 1)
#pragma unroll
    for (int p = 0; p < 4; p++) sc[p] += __shfl_xor(sc[p], off, 16);
  float m = fmaxf(fmaxf(sc[0], sc[1]), fmaxf(sc[2], sc[3]));
  float e[4], sum = 0.f;
#pragma unroll
  for (int p = 0; p < 4; p++) { e[p] = __expf((sc[p] - m) * 0.088388347648318447f); sum += e[p]; }
  float inv = 1.0f / sum;
  float o[8] = {};
#pragma unroll
  for (int p = 0; p < 4; p++) {
    half8v vv = *(const half8v*)(vh + p * DM + h * HD + d);
#pragma unroll
    for (int j = 0; j < 8; j++) o[j] += e[p] * (float)vv[j];
  }
  half8v ov;
#pragma unroll
  for (int j = 0; j < 8; j++) ov[j] = (half_t)(o[j] * inv);
  *(half8v*)(ipout + (long)s * DM + h * HD + d) = ov;
}

// ------------------------------------------------ flash attention, KVBLK=64, 2-buf 1-ahead
// Blocks >= 480 convert Wo/Wao f32->f16 into the out-weight slots (hidden under flash).
__global__ __launch_bounds__(256, 2) void flash_kernel(const half_t* __restrict__ qcat,
                                                       const half_t* __restrict__ kcat,
                                                       const half_t* __restrict__ vcatT,
                                                       const half_t* __restrict__ ipout,
                                                       const float* __restrict__ lsp,
                                                       half_t* __restrict__ ocomb,
                                                       const float* __restrict__ WoF,
                                                       const float* __restrict__ WaoF,
                                                       half_t* __restrict__ w0d,
                                                       half_t* __restrict__ w1d) {
  __shared__ half_t Ks[2 * 64 * 128];  // 32 KB, rows 256B XOR-swizzled
  __shared__ half_t Vs[2 * 128 * 64];  // 32 KB, rows 128B XOR-swizzled
  if (blockIdx.x >= 480) {             // embedded weight-convert blocks
    int cb = blockIdx.x - 480;
    long i = ((long)cb * 256 + threadIdx.x) * 8;
    long stride = (long)(gridDim.x - 480) * 256 * 8;
    for (; i < 2 * WSZC; i += stride) {
      if (i < WSZC) cvt8span(WoF, w0d, i);
      else          cvt8span(WaoF, w1d, i - WSZC);
    }
    return;
  }
  int b = blockIdx.x;
  int wg = (b & 7) * 60 + (b >> 3);    // bijective XCD swizzle (480 = 8x60)
  const int h = wg / 20, qb = wg % 20;
  const int tid = threadIdx.x, wid = tid >> 6, l = tid & 63;
  const int l15 = l & 15, l4 = l >> 4;
  const float CEXP = 0.12754137969983614f;  // (1/sqrt(128)) * log2(e)

  half8v qf[2][4];
#pragma unroll
  for (int t = 0; t < 2; t++) {
    int qrow = qb * 128 + wid * 32 + t * 16 + l15;
    const half_t* qp = qcat + ((long)h * S_TOT + qrow) * HD;
#pragma unroll
    for (int kk = 0; kk < 4; kk++) qf[t][kk] = *(const half8v*)(qp + kk * 32 + l4 * 8);
  }
  float4v o[2][8] = {};
  float lsum[2] = {0.f, 0.f};
  const float ls = lsp[0];

  const char* kb = (const char*)(kcat + (long)h * S_TOT * HD);
  const char* vb = (const char*)(vcatT + (long)h * HD * S_TOT);
  int kof[4];
  long vof[4];
#pragma unroll
  for (int c = 0; c < 4; c++) {
    int L = c * 4096 + tid * 16;
    kof[c] = L ^ (((L >> 8) & 7) << 4);
    int vrow = L >> 7;
    vof[c] = (long)vrow * (S_TOT * 2) + ((L & 127) ^ ((vrow & 7) << 4));
  }

#define STAGE(KT, SEL)                                                        \
  {                                                                           \
    char* kd = (char*)Ks + (SEL) * 16384 + wid * 1024;                        \
    char* vd = (char*)Vs + (SEL) * 16384 + wid * 1024;                        \
    _Pragma("unroll") for (int c = 0; c < 4; c++) {                           \
      gload16(kb + (long)(KT) * 256 + kof[c], kd + c * 4096);                 \
      gload16(vb + vof[c] + (KT) * 2, vd + c * 4096);                         \
    }                                                                         \
  }

  STAGE(0, 0);

  const int NT = S_TOT / 64;  // 40
  int sel = 0;
  for (int it = 0; it < NT; it++) {
    asm volatile("s_waitcnt vmcnt(0)" ::: "memory");
    __builtin_amdgcn_s_barrier();
    __builtin_amdgcn_sched_barrier(0);
    if (it + 1 < NT) STAGE((it + 1) * 64, sel ^ 1);

    const char* KsB = (const char*)Ks + sel * 16384;
    const char* VsB = (const char*)Vs + sel * 16384;

    float4v s0[4] = {}, s1[4] = {};
    __builtin_amdgcn_s_setprio(1);
#pragma unroll
    for (int nb = 0; nb < 4; nb++) {
      int krow = nb * 16 + l15;
      int rb = krow << 8;
      int sw = (krow & 7) << 4;
#pragma unroll
      for (int kk = 0; kk < 4; kk++) {
        half8v kf = *(const half8v*)(KsB + rb + ((kk * 64 + l4 * 16) ^ sw));
        s0[nb] = __builtin_amdgcn_mfma_f32_16x16x32_f16(kf, qf[0][kk], s0[nb], 0, 0, 0);
        s1[nb] = __builtin_amdgcn_mfma_f32_16x16x32_f16(kf, qf[1][kk], s1[nb], 0, 0, 0);
      }
    }
    __builtin_amdgcn_s_setprio(0);
    half8v pa00, pa01, pa10, pa11;
    {
      float sum0 = 0.f, sum1 = 0.f;
      float e0[4][4], e1[4][4];
#pragma unroll
      for (int nb = 0; nb < 4; nb++)
#pragma unroll
        for (int r = 0; r < 4; r++) {
          float a = exp2f(s0[nb][r] * CEXP - 2.0f);
          float c = exp2f(s1[nb][r] * CEXP - 2.0f);
          e0[nb][r] = a; e1[nb][r] = c;
          sum0 += a; sum1 += c;
        }
      lsum[0] += sum0; lsum[1] += sum1;
#pragma unroll
      for (int r = 0; r < 4; r++) {
        pa00[r] = (half_t)e0[0][r]; pa00[r + 4] = (half_t)e0[1][r];
        pa01[r] = (half_t)e0[2][r]; pa01[r + 4] = (half_t)e0[3][r];
        pa10[r] = (half_t)e1[0][r]; pa10[r + 4] = (half_t)e1[1][r];
        pa11[r] = (half_t)e1[2][r]; pa11[r + 4] = (half_t)e1[3][r];
      }
    }
    __builtin_amdgcn_s_setprio(1);
#pragma unroll
    for (int cb = 0; cb < 8; cb++) {
      int row = cb * 16 + l15;
      int sw = (row & 7) << 4;
      half8v vf0 = *(const half8v*)(VsB + (row << 7) + ((l4 * 16) ^ sw));
      half8v vf1 = *(const half8v*)(VsB + (row << 7) + ((64 + l4 * 16) ^ sw));
      o[0][cb] = __builtin_amdgcn_mfma_f32_16x16x32_f16(pa00, vf0, o[0][cb], 0, 0, 0);
      o[0][cb] = __builtin_amdgcn_mfma_f32_16x16x32_f16(pa01, vf1, o[0][cb], 0, 0, 0);
      o[1][cb] = __builtin_amdgcn_mfma_f32_16x16x32_f16(pa10, vf0, o[1][cb], 0, 0, 0);
      o[1][cb] = __builtin_amdgcn_mfma_f32_16x16x32_f16(pa11, vf1, o[1][cb], 0, 0, 0);
    }
    __builtin_amdgcn_s_setprio(0);
    sel ^= 1;
  }
#undef STAGE
  float lreg[2];
#pragma unroll
  for (int t = 0; t < 2; t++) {
    float s = lsum[t];
    s += __shfl_xor(s, 16, 64);
    s += __shfl_xor(s, 32, 64);
    lreg[t] = s;
  }
#pragma unroll
  for (int t = 0; t < 2; t++) {
    float invq = 1.0f / lreg[t];
#pragma unroll
    for (int r = 0; r < 4; r++) {
      float inv = __shfl(invq, l4 * 4 + r, 64);
      int s = qb * 128 + wid * 32 + t * 16 + l4 * 4 + r;
#pragma unroll
      for (int cb = 0; cb < 8; cb++) {
        int col = h * HD + cb * 16 + l15;
        float val = o[t][cb][r] * inv;
        if (s >= S_TXT) val += ls * (float)ipout[(long)(s - S_TXT) * DM + col];
        ocomb[(long)s * DM + col] = (half_t)val;
      }
    }
  }
}

// ================================================================ host
extern "C" void kernel_launch(void* const* d_in, const int* in_sizes, int n_in,
                              void* d_out, int out_size, void* d_ws, size_t ws_size,
                              hipStream_t stream) {
  (void)in_sizes; (void)n_in; (void)out_size; (void)ws_size;
  const float* hs    = (const float*)d_in[0];
  const float* enc   = (const float*)d_in[1];
  const float* ipenc = (const float*)d_in[2];
  const float* lsc   = (const float*)d_in[3];
  const float* Wq  = (const float*)d_in[4];  const float* bq  = (const float*)d_in[5];
  const float* Wk  = (const float*)d_in[6];  const float* bk  = (const float*)d_in[7];
  const float* Wv  = (const float*)d_in[8];  const float* bv  = (const float*)d_in[9];
  const float* nqw = (const float*)d_in[10]; const float* nkw = (const float*)d_in[11];
  const float* Waq = (const float*)d_in[12]; const float* baq = (const float*)d_in[13];
  const float* Wak = (const float*)d_in[14]; const float* bak = (const float*)d_in[15];
  const float* Wav = (const float*)d_in[16]; const float* bav = (const float*)d_in[17];
  const float* naqw= (const float*)d_in[18]; const float* nakw= (const float*)d_in[19];
  const float* Wkip= (const float*)d_in[20]; const float* Wvip= (const float*)d_in[21];
  const float* Wo  = (const float*)d_in[22]; const float* bo  = (const float*)d_in[23];
  const float* Wao = (const float*)d_in[24]; const float* bao = (const float*)d_in[25];
  const float* cosb= (const float*)d_in[26]; const float* sinb= (const float*)d_in[27];

  const size_t WSZ = WSZC;
  const size_t HSZ = HSZC;
  const size_t ESZ = ESZC;
  const size_t CSZ = (size_t)NH * S_TOT * HD;

  half_t* base = (half_t*)d_ws;
  half_t* Wsl   = base;                 // 2 slots for Wo/Wao f16
  half_t* hs_h  = Wsl + 2 * WSZ;
  half_t* enc_h = hs_h + HSZ;           // contiguous after hs_h
  half_t* qkvr  = enc_h + ESZ;
  half_t* eqkv  = qkvr + 3 * HSZ;
  half_t* qcat  = eqkv + 3 * ESZ;
  half_t* kcat  = qcat + CSZ;
  half_t* vcatT = kcat + CSZ;

  half_t* q_raw = qkvr;
  half_t* k_raw = qkvr + HSZ;
  half_t* v_raw = qkvr + 2 * HSZ;
  half_t* eq_r  = eqkv;
  half_t* ek_r  = eqkv + ESZ;
  half_t* ev_r  = eqkv + 2 * ESZ;
  // aliases (stream-order safe)
  half_t* qnr   = hs_h;
  half_t* ipout = qkvr;
  half_t* ocomb = qkvr + HSZ;
  float*  ipk_raw = (float*)enc_h;
  float*  ipv_raw = ipk_raw + 4 * DM;
  half_t* ipk_h  = enc_h + 16 * DM;
  half_t* ipv_h  = ipk_h + 4 * DM;

  // activations -> f16 (weights NOT converted: QKV GEMM stages f32 directly)
  cvt_act_kernel<<<2048, 256, 0, stream>>>(hs, enc, hs_h);

  // merged img+enc QKV GEMM, f32-direct weights (1440 blocks, XCD swizzle)
  gemm_qkv_kernel<<<1440, 256, 0, stream>>>(hs_h, enc_h,
                                            Wq, Wk, Wv, Waq, Wak, Wav,
                                            bq, bk, bv, baq, bak, bav,
                                            q_raw, k_raw, v_raw, eq_r, ek_r, ev_r);

  // ip path (merged k/v projections)
  ip_proj_kernel<<<dim3(768, 2), 256, 0, stream>>>(ipenc, Wkip, Wvip, ipk_raw, ipv_raw);
  ip_norm_kernel<<<192, 64, 0, stream>>>(ipk_raw, ipv_raw, ipk_h, ipv_h);

  // merged prep + vtrans (15360 prep blocks + 960 vtrans tiles)
  prep_vtrans_kernel<<<16320, 256, 0, stream>>>(q_raw, k_raw, eq_r, ek_r, ev_r, v_raw,
                                                nqw, nkw, naqw, nakw, cosb, sinb,
                                                qcat, kcat, qnr, vcatT);

  // ip attention (overwrites q_raw region)
  ip_attn_kernel<<<(NH * S_IMG) / 16, 256, 0, stream>>>(qnr, ipk_h, ipv_h, ipout);

  // main flash attention + embedded Wo/Wao f32->f16 convert
  flash_kernel<<<480 + 512, 256, 0, stream>>>(qcat, kcat, vcatT, ipout, lsc, ocomb,
                                              Wo, Wao, Wsl, Wsl + WSZ);

  // output projections -> d_out f32 (f16 weights from slots 0,1)
  float* out_img = (float*)d_out;
  float* out_enc = (float*)d_out + (size_t)S_IMG * DM;
  gemm_out_kernel<<<480, 256, 0, stream>>>(ocomb, Wsl, Wsl + WSZ, bo, bao, out_img, out_enc);
}

// Round 19
// 501.921 us; speedup vs baseline: 1.0425x; 1.0425x over previous
//
#include <hip/hip_runtime.h>

typedef _Float16 half_t;
typedef _Float16 half2v __attribute__((ext_vector_type(2)));
typedef _Float16 half4v __attribute__((ext_vector_type(4)));
typedef _Float16 half8v __attribute__((ext_vector_type(8)));
typedef float    float4v __attribute__((ext_vector_type(4)));
typedef short    short8v __attribute__((ext_vector_type(8)));

#define S_IMG 2048
#define S_TXT 512
#define S_TOT 2560
#define NH    24
#define HD    128
#define DM    3072
#define WSZC  9437184L   // DM*DM
#define HSZC  6291456L   // S_IMG*DM
#define ESZC  1572864L   // S_TXT*DM

// async global->LDS, 16B per lane, wave-uniform LDS base (+ lane*16 by HW)
__device__ __forceinline__ void gload16(const void* g, void* l) {
  __builtin_amdgcn_global_load_lds(
      (const __attribute__((address_space(1))) unsigned int*)g,
      (__attribute__((address_space(3))) unsigned int*)l, 16, 0, 0);
}

__device__ __forceinline__ void cvt8span(const float* s, half_t* d, long i) {
  float4v v0 = *(const float4v*)(s + i);
  float4v v1 = *(const float4v*)(s + i + 4);
  half8v h;
  h[0] = (half_t)v0[0]; h[1] = (half_t)v0[1]; h[2] = (half_t)v0[2]; h[3] = (half_t)v0[3];
  h[4] = (half_t)v1[0]; h[5] = (half_t)v1[1]; h[6] = (half_t)v1[2]; h[7] = (half_t)v1[3];
  *(half8v*)(d + i) = h;
}

// ---------------------------------------------------------------- activations -> f16 (merged)
__global__ void cvt_act_kernel(const float* __restrict__ hs, const float* __restrict__ enc,
                               half_t* __restrict__ d) {
  const long TOT = HSZC + ESZC;
  long i = ((long)blockIdx.x * 256 + threadIdx.x) * 8;
  long stride = (long)gridDim.x * 256 * 8;
  for (; i < TOT; i += stride) {
    const float* s = i < HSZC ? hs + i : enc + (i - HSZC);
    cvt8span(s, d + i, 0);
  }
}

// merged 2/3-region weight convert; region = blockIdx.y (fallback path)
__global__ void cvt3_kernel(const float* __restrict__ s0, const float* __restrict__ s1,
                            const float* __restrict__ s2,
                            half_t* __restrict__ d0, half_t* __restrict__ d1,
                            half_t* __restrict__ d2, int n) {
  const float* s = blockIdx.y == 0 ? s0 : (blockIdx.y == 1 ? s1 : s2);
  half_t* d = blockIdx.y == 0 ? d0 : (blockIdx.y == 1 ? d1 : d2);
  long i = ((long)blockIdx.x * 256 + threadIdx.x) * 8;
  long stride = (long)gridDim.x * 256 * 8;
  for (; i < n; i += stride) cvt8span(s, d, i);
}

// 8-region convert: y=0..5 -> weights into W6 slots; y=6 hs; y=7 enc (big path)
__global__ void cvt8_kernel(const float* w0, const float* w1, const float* w2,
                            const float* w3, const float* w4, const float* w5,
                            const float* hs, const float* enc,
                            half_t* __restrict__ W6, half_t* __restrict__ hs_h) {
  int y = blockIdx.y;
  const float* s;
  half_t* d;
  long n;
  if (y < 6) {
    s = y == 0 ? w0 : y == 1 ? w1 : y == 2 ? w2 : y == 3 ? w3 : y == 4 ? w4 : w5;
    d = W6 + (long)y * WSZC;
    n = WSZC;
  } else if (y == 6) { s = hs; d = hs_h; n = HSZC; }
  else               { s = enc; d = hs_h + HSZC; n = ESZC; }
  long i = ((long)blockIdx.x * 256 + threadIdx.x) * 8;
  long stride = (long)gridDim.x * 256 * 8;
  for (; i < n; i += stride) cvt8span(s, d, i);
}

// ------------------------------------------------ 128x128 GEMM tile body
// 2-buffer 1-ahead pipeline: vmcnt(0) -> barrier -> stage(t+1) -> compute(t).
// 64B-row XOR swizzle (slot ^= (row>>1)&3).
template <typename OUT>
__device__ __forceinline__ void gemm_tile(half_t* As, half_t* Bs,  // each 2*4096 halves
                                          const half_t* __restrict__ A,
                                          const half_t* __restrict__ Bt,
                                          const float* __restrict__ bias,
                                          OUT* __restrict__ C, int bm, int bn) {
  const int K = DM, N = DM;
  const int tid = threadIdx.x, wid = tid >> 6, l = tid & 63;
  const int wm = (wid >> 1) * 64, wn = (wid & 1) * 64;
  const int l15 = l & 15, l4 = l >> 4;
  float4v acc[4][4] = {};

  const int scol = ((l & 3) ^ ((l >> 3) & 3)) * 8;
  const half_t* ga = A + (long)(bm + wid * 32 + (l >> 2)) * K + scol;
  const half_t* gb = Bt + (long)(bn + wid * 32 + (l >> 2)) * K + scol;
  const long rowstep = 16l * K;

#define GSTAGE(T, SEL)                                                        \
  {                                                                           \
    char* a_d = (char*)As + (SEL) * 8192 + wid * 2048;                        \
    char* b_d = (char*)Bs + (SEL) * 8192 + wid * 2048;                        \
    int k0 = (T) * 32;                                                        \
    gload16(ga + k0, a_d);                                                    \
    gload16(ga + rowstep + k0, a_d + 1024);                                   \
    gload16(gb + k0, b_d);                                                    \
    gload16(gb + rowstep + k0, b_d + 1024);                                   \
  }

  GSTAGE(0, 0);

  const int NT = K / 32;  // 96
  const int cofs = (l4 * 16) ^ (((l15 >> 1) & 3) << 4);  // swizzled byte-in-row
  int sel = 0;
  for (int t = 0; t < NT; t++) {
    asm volatile("s_waitcnt vmcnt(0)" ::: "memory");
    __builtin_amdgcn_s_barrier();
    __builtin_amdgcn_sched_barrier(0);
    if (t + 1 < NT) GSTAGE(t + 1, sel ^ 1);
    __builtin_amdgcn_sched_barrier(0);
    const char* AsB = (const char*)As + sel * 8192;
    const char* BsB = (const char*)Bs + sel * 8192;
    half8v af[4], bf[4];
#pragma unroll
    for (int i = 0; i < 4; i++)
      af[i] = *(const half8v*)(AsB + (wm + i * 16 + l15) * 64 + cofs);
#pragma unroll
    for (int j = 0; j < 4; j++)
      bf[j] = *(const half8v*)(BsB + (wn + j * 16 + l15) * 64 + cofs);
    __builtin_amdgcn_s_setprio(1);
#pragma unroll
    for (int i = 0; i < 4; i++)
#pragma unroll
      for (int j = 0; j < 4; j++)
        acc[i][j] = __builtin_amdgcn_mfma_f32_16x16x32_f16(af[i], bf[j], acc[i][j], 0, 0, 0);
    __builtin_amdgcn_s_setprio(0);
    sel ^= 1;
  }
#undef GSTAGE
#pragma unroll
  for (int i = 0; i < 4; i++)
#pragma unroll
    for (int j = 0; j < 4; j++) {
      int row = bm + wm + i * 16 + l4 * 4;
      int col = bn + wn + j * 16 + l15;
      float bv = bias ? bias[col] : 0.0f;
#pragma unroll
      for (int r = 0; r < 4; r++) {
        float v = acc[i][j][r] + bv;
        C[(long)(row + r) * N + col] = (OUT)v;
      }
    }
}

// merged img+enc QKV GEMM: 1440 = 1152 img + 288 enc, bijective XCD swizzle (8x180)
__global__ __launch_bounds__(256) void gemm_qkv_kernel(
    const half_t* __restrict__ hs_h, const half_t* __restrict__ enc_h,
    const half_t* __restrict__ W6,
    const float* bq, const float* bk, const float* bv,
    const float* baq, const float* bak, const float* bav,
    half_t* q_raw, half_t* k_raw, half_t* v_raw,
    half_t* eq_r, half_t* ek_r, half_t* ev_r) {
  __shared__ half_t As[2 * 4096];
  __shared__ half_t Bs[2 * 4096];
  int b = blockIdx.x;
  int wg = (b & 7) * 180 + (b >> 3);
  const half_t* A;
  const half_t* Bt;
  const float* bias;
  half_t* C;
  int bm, bn;
  if (wg < 1152) {
    int col = wg / 16, row = wg % 16;
    int sel = col / 24;
    A = hs_h; bm = row * 128; bn = (col % 24) * 128;
    Bt = W6 + (long)sel * WSZC;
    bias = sel == 0 ? bq : (sel == 1 ? bk : bv);
    C = sel == 0 ? q_raw : (sel == 1 ? k_raw : v_raw);
  } else {
    int w2 = wg - 1152;
    int col = w2 / 4, row = w2 % 4;
    int sel = col / 24;
    A = enc_h; bm = row * 128; bn = (col % 24) * 128;
    Bt = W6 + (long)(3 + sel) * WSZC;
    bias = sel == 0 ? baq : (sel == 1 ? bak : bav);
    C = sel == 0 ? eq_r : (sel == 1 ? ek_r : ev_r);
  }
  gemm_tile<half_t>(As, Bs, A, Bt, bias, C, bm, bn);
}

// fallback: fused triple-GEMM, 1D XCD-swizzled grid; NROW row-blocks, 72 col-blocks
template <int NROW>
__global__ __launch_bounds__(256) void gemm3_kernel(const half_t* __restrict__ A,
                                                    const half_t* __restrict__ W0,
                                                    const half_t* __restrict__ W1,
                                                    const half_t* __restrict__ W2,
                                                    const float* b0, const float* b1, const float* b2,
                                                    half_t* O0, half_t* O1, half_t* O2) {
  __shared__ half_t As[2 * 4096];
  __shared__ half_t Bs[2 * 4096];
  int b = blockIdx.x;
  int q = (72 * NROW) >> 3;
  int wg = (b & 7) * q + (b >> 3);
  int col = wg / NROW, row = wg % NROW;
  int sel = col / 24;
  const half_t* Bt = sel == 0 ? W0 : (sel == 1 ? W1 : W2);
  const float* bias = sel == 0 ? b0 : (sel == 1 ? b1 : b2);
  half_t* C = sel == 0 ? O0 : (sel == 1 ? O1 : O2);
  gemm_tile<half_t>(As, Bs, A, Bt, bias, C, row * 128, (col % 24) * 128);
}

// fused output projections; 1D grid 480 = 8 x 60; r<16 img, r>=16 enc
__global__ __launch_bounds__(256) void gemm_out_kernel(const half_t* __restrict__ ocomb,
                                                       const half_t* __restrict__ Wo_h,
                                                       const half_t* __restrict__ Wao_h,
                                                       const float* bo, const float* bao,
                                                       float* out_img, float* out_enc) {
  __shared__ half_t As[2 * 4096];
  __shared__ half_t Bs[2 * 4096];
  int b = blockIdx.x;
  int wg = (b & 7) * 60 + (b >> 3);
  int col = wg / 20, r = wg % 20;
  bool enc = r >= 16;
  const half_t* A = enc ? ocomb : ocomb + (long)S_TXT * DM;
  int bm = (enc ? (r - 16) : r) * 128;
  gemm_tile<float>(As, Bs, A, enc ? Wao_h : Wo_h, enc ? bao : bo,
                   enc ? out_enc : out_img, bm, col * 128);
}

// ------------------------------------------------ ip projections (M=4, f32 direct), merged k/v
__global__ __launch_bounds__(256) void ip_proj_kernel(const float* __restrict__ x,
                                                      const float* __restrict__ Wk_ip,
                                                      const float* __restrict__ Wv_ip,
                                                      float* __restrict__ outk,
                                                      float* __restrict__ outv) {
  const float* W = blockIdx.y ? Wv_ip : Wk_ip;
  float* out = blockIdx.y ? outv : outk;
  int n = blockIdx.x * 4 + (threadIdx.x >> 6);
  int l = threadIdx.x & 63;
  const float* wr = W + (long)n * DM;
  float acc[4] = {0.f, 0.f, 0.f, 0.f};
  for (int k = l * 4; k < DM; k += 256) {
    float4v wv = *(const float4v*)(wr + k);
#pragma unroll
    for (int p = 0; p < 4; p++) {
      float4v xv = *(const float4v*)(x + p * DM + k);
      acc[p] += wv[0] * xv[0] + wv[1] * xv[1] + wv[2] * xv[2] + wv[3] * xv[3];
    }
  }
#pragma unroll
  for (int off = 32; off; off >>= 1)
#pragma unroll
    for (int p = 0; p < 4; p++) acc[p] += __shfl_xor(acc[p], off, 64);
  if (l == 0)
#pragma unroll
    for (int p = 0; p < 4; p++) out[p * DM + n] = acc[p];
}

// ------------------------------------------------ ip k-norm (eps 1e-5) + v convert
__global__ void ip_norm_kernel(const float* __restrict__ kr, const float* __restrict__ vr,
                               half_t* __restrict__ kh, half_t* __restrict__ vh) {
  int t = blockIdx.x;
  int l = threadIdx.x;
  int d = l * 2;
  if (t < 96) {
    int base = (t / 24) * DM + (t % 24) * HD;
    float x0 = kr[base + d], x1 = kr[base + d + 1];
    float ss = x0 * x0 + x1 * x1;
#pragma unroll
    for (int off = 32; off; off >>= 1) ss += __shfl_xor(ss, off, 64);
    float r = rsqrtf(ss * (1.0f / HD) + 1e-5f);
    kh[base + d] = (half_t)(x0 * r);
    kh[base + d + 1] = (half_t)(x1 * r);
  } else {
    int t2 = t - 96;
    int base = (t2 / 24) * DM + (t2 % 24) * HD;
    vh[base + d] = (half_t)vr[base + d];
    vh[base + d + 1] = (half_t)vr[base + d + 1];
  }
}

// ------------------------------------------------ merged prep (rmsnorm+rope+concat) + vtrans
// blocks < 15360: prep rows; blocks >= 15360: V transpose+pi-permute tiles
__global__ __launch_bounds__(256) void prep_vtrans_kernel(
    const half_t* __restrict__ qraw, const half_t* __restrict__ kraw,
    const half_t* __restrict__ eq, const half_t* __restrict__ ek,
    const half_t* __restrict__ ev, const half_t* __restrict__ vraw,
    const float* __restrict__ nqw, const float* __restrict__ nkw,
    const float* __restrict__ naqw, const float* __restrict__ nakw,
    const float* __restrict__ cosb, const float* __restrict__ sinb,
    half_t* __restrict__ qcat, half_t* __restrict__ kcat, half_t* __restrict__ qnr,
    half_t* __restrict__ vcatT) {
  __shared__ half_t T[64][136];
  if (blockIdx.x < 15360) {
    int task = blockIdx.x * 4 + (threadIdx.x >> 6);
    int l = threadIdx.x & 63;
    int s = task / NH, h = task - (task / NH) * NH;
    int d = l * 2;
    const half_t *qs, *ks;
    const float *wq, *wk;
    if (s < S_TXT) {
      long base = (long)s * DM + h * HD;
      qs = eq + base; ks = ek + base;
      wq = naqw; wk = nakw;
    } else {
      long base = (long)(s - S_TXT) * DM + h * HD;
      qs = qraw + base; ks = kraw + base;
      wq = nqw; wk = nkw;
    }
    half2v qv = *(const half2v*)(qs + d);
    half2v kv = *(const half2v*)(ks + d);
    float q0 = (float)qv[0], q1 = (float)qv[1];
    float k0 = (float)kv[0], k1 = (float)kv[1];
    float ssq = q0 * q0 + q1 * q1;
    float ssk = k0 * k0 + k1 * k1;
#pragma unroll
    for (int off = 32; off; off >>= 1) {
      ssq += __shfl_xor(ssq, off, 64);
      ssk += __shfl_xor(ssk, off, 64);
    }
    float rq = rsqrtf(ssq * (1.0f / HD) + 1e-6f);
    float rk = rsqrtf(ssk * (1.0f / HD) + 1e-6f);
    float qn0 = q0 * rq * wq[d], qn1 = q1 * rq * wq[d + 1];
    float kn0 = k0 * rk * wk[d], kn1 = k1 * rk * wk[d + 1];
    if (s >= S_TXT) {
      half2v o; o[0] = (half_t)qn0; o[1] = (half_t)qn1;
      *(half2v*)(qnr + ((long)h * S_IMG + (s - S_TXT)) * HD + d) = o;
    }
    float c0 = cosb[s * HD + d], c1 = cosb[s * HD + d + 1];
    float s0 = sinb[s * HD + d], s1 = sinb[s * HD + d + 1];
    float qo0 = qn0 * c0 - qn1 * s0, qo1 = qn1 * c1 + qn0 * s1;
    float ko0 = kn0 * c0 - kn1 * s0, ko1 = kn1 * c1 + kn0 * s1;
    long ci = ((long)h * S_TOT + s) * HD + d;
    half2v oq; oq[0] = (half_t)qo0; oq[1] = (half_t)qo1;
    half2v ok; ok[0] = (half_t)ko0; ok[1] = (half_t)ko1;
    *(half2v*)(qcat + ci) = oq;
    *(half2v*)(kcat + ci) = ok;
  } else {
    int b2 = blockIdx.x - 15360;       // 960 tiles = 24 heads x 40 s-blocks
    int h = b2 / 40, sb = (b2 % 40) * 64;
    int t = threadIdx.x;
#pragma unroll
    for (int i = 0; i < 4; i++) {
      int c = t + i * 256;
      int row = c >> 4, col = (c & 15) * 8;
      int s = sb + row;
      const half_t* src = (s < S_TXT) ? ev + (long)s * DM + h * HD + col
                                      : vraw + (long)(s - S_TXT) * DM + h * HD + col;
      *(half8v*)&T[row][col] = *(const half8v*)src;
    }
    __syncthreads();
#pragma unroll
    for (int i = 0; i < 4; i++) {
      int c = t + i * 256;
      int d = c >> 3, sc = (c & 7) * 8;
      half8v v;
#pragma unroll
      for (int j = 0; j < 8; j++) v[j] = T[sc + j][d];
      // pi^{-1}: dst_b4 = s_b3, dst_b3 = s_b2, dst_b2 = s_b4 (3-cycle)
      int base = (sc & 32) | ((sc & 8) << 1) | ((sc & 16) >> 2);
      half_t* dst = vcatT + ((long)h * HD + d) * S_TOT + sb;
      half4v q0; q0[0] = v[0]; q0[1] = v[1]; q0[2] = v[2]; q0[3] = v[3];
      half4v q1; q1[0] = v[4]; q1[1] = v[5]; q1[2] = v[6]; q1[7 - 7] = q1[0]; q1[0] = v[4]; q1[1] = v[5]; q1[2] = v[6]; q1[3] = v[7];
      *(half4v*)(dst + base) = q0;
      *(half4v*)(dst + base + 8) = q1;
    }
  }
}

// ------------------------------------------------ ip attention (4 keys), 8 halves/lane
__global__ __launch_bounds__(256) void ip_attn_kernel(const half_t* __restrict__ qnr,
                                                      const half_t* __restrict__ kh,
                                                      const half_t* __restrict__ vh,
                                                      half_t* __restrict__ ipout) {
  int tid = threadIdx.x;
  int task = blockIdx.x * 16 + (tid >> 4);
  int l16 = tid & 15;
  int h = task >> 11;
  int s = task & 2047;
  int d = l16 * 8;
  half8v qv = *(const half8v*)(qnr + ((long)h * S_IMG + s) * HD + d);
  float sc[4];
#pragma unroll
  for (int p = 0; p < 4; p++) {
    half8v kv = *(const half8v*)(kh + p * DM + h * HD + d);
    float a = 0.f;
#pragma unroll
    for (int j = 0; j < 8; j++) a += (float)qv[j] * (float)kv[j];
    sc[p] = a;
  }
#pragma unroll
  for (int off = 8; off; off >>= 1)
#pragma unroll
    for (int p = 0; p < 4; p++) sc[p] += __shfl_xor(sc[p], off, 16);
  float m = fmaxf(fmaxf(sc[0], sc[1]), fmaxf(sc[2], sc[3]));
  float e[4], sum = 0.f;
#pragma unroll
  for (int p = 0; p < 4; p++) { e[p] = __expf((sc[p] - m) * 0.088388347648318447f); sum += e[p]; }
  float inv = 1.0f / sum;
  float o[8] = {};
#pragma unroll
  for (int p = 0; p < 4; p++) {
    half8v vv = *(const half8v*)(vh + p * DM + h * HD + d);
#pragma unroll
    for (int j = 0; j < 8; j++) o[j] += e[p] * (float)vv[j];
  }
  half8v ov;
#pragma unroll
  for (int j = 0; j < 8; j++) ov[j] = (half_t)(o[j] * inv);
  *(half8v*)(ipout + (long)s * DM + h * HD + d) = ov;
}

// ------------------------------------------------ flash attention, KVBLK=64, 2-buf 1-ahead
// Blocks >= 480 (big-ws path only) convert Wo/Wao f32->f16 into dead weight slots.
__global__ __launch_bounds__(256, 2) void flash_kernel(const half_t* __restrict__ qcat,
                                                       const half_t* __restrict__ kcat,
                                                       const half_t* __restrict__ vcatT,
                                                       const half_t* __restrict__ ipout,
                                                       const float* __restrict__ lsp,
                                                       half_t* __restrict__ ocomb,
                                                       const float* __restrict__ WoF,
                                                       const float* __restrict__ WaoF,
                                                       half_t* __restrict__ w0d,
                                                       half_t* __restrict__ w1d) {
  __shared__ half_t Ks[2 * 64 * 128];  // 32 KB, rows 256B XOR-swizzled
  __shared__ half_t Vs[2 * 128 * 64];  // 32 KB, rows 128B XOR-swizzled
  if (blockIdx.x >= 480) {             // embedded weight-convert blocks
    int cb = blockIdx.x - 480;
    long i = ((long)cb * 256 + threadIdx.x) * 8;
    long stride = (long)(gridDim.x - 480) * 256 * 8;
    for (; i < 2 * WSZC; i += stride) {
      if (i < WSZC) cvt8span(WoF, w0d, i);
      else          cvt8span(WaoF, w1d, i - WSZC);
    }
    return;
  }
  int b = blockIdx.x;
  int wg = (b & 7) * 60 + (b >> 3);    // bijective XCD swizzle (480 = 8x60)
  const int h = wg / 20, qb = wg % 20;
  const int tid = threadIdx.x, wid = tid >> 6, l = tid & 63;
  const int l15 = l & 15, l4 = l >> 4;
  const float CEXP = 0.12754137969983614f;  // (1/sqrt(128)) * log2(e)

  half8v qf[2][4];
#pragma unroll
  for (int t = 0; t < 2; t++) {
    int qrow = qb * 128 + wid * 32 + t * 16 + l15;
    const half_t* qp = qcat + ((long)h * S_TOT + qrow) * HD;
#pragma unroll
    for (int kk = 0; kk < 4; kk++) qf[t][kk] = *(const half8v*)(qp + kk * 32 + l4 * 8);
  }
  float4v o[2][8] = {};
  float lsum[2] = {0.f, 0.f};
  const float ls = lsp[0];

  const char* kb = (const char*)(kcat + (long)h * S_TOT * HD);
  const char* vb = (const char*)(vcatT + (long)h * HD * S_TOT);
  int kof[4];
  long vof[4];
#pragma unroll
  for (int c = 0; c < 4; c++) {
    int L = c * 4096 + tid * 16;
    kof[c] = L ^ (((L >> 8) & 7) << 4);
    int vrow = L >> 7;
    vof[c] = (long)vrow * (S_TOT * 2) + ((L & 127) ^ ((vrow & 7) << 4));
  }

#define STAGE(KT, SEL)                                                        \
  {                                                                           \
    char* kd = (char*)Ks + (SEL) * 16384 + wid * 1024;                        \
    char* vd = (char*)Vs + (SEL) * 16384 + wid * 1024;                        \
    _Pragma("unroll") for (int c = 0; c < 4; c++) {                           \
      gload16(kb + (long)(KT) * 256 + kof[c], kd + c * 4096);                 \
      gload16(vb + vof[c] + (KT) * 2, vd + c * 4096);                         \
    }                                                                         \
  }

  STAGE(0, 0);

  const int NT = S_TOT / 64;  // 40
  int sel = 0;
  for (int it = 0; it < NT; it++) {
    asm volatile("s_waitcnt vmcnt(0)" ::: "memory");
    __builtin_amdgcn_s_barrier();
    __builtin_amdgcn_sched_barrier(0);
    if (it + 1 < NT) STAGE((it + 1) * 64, sel ^ 1);

    const char* KsB = (const char*)Ks + sel * 16384;
    const char* VsB = (const char*)Vs + sel * 16384;

    float4v s0[4] = {}, s1[4] = {};
    __builtin_amdgcn_s_setprio(1);
#pragma unroll
    for (int nb = 0; nb < 4; nb++) {
      int krow = nb * 16 + l15;
      int rb = krow << 8;
      int sw = (krow & 7) << 4;
#pragma unroll
      for (int kk = 0; kk < 4; kk++) {
        half8v kf = *(const half8v*)(KsB + rb + ((kk * 64 + l4 * 16) ^ sw));
        s0[nb] = __builtin_amdgcn_mfma_f32_16x16x32_f16(kf, qf[0][kk], s0[nb], 0, 0, 0);
        s1[nb] = __builtin_amdgcn_mfma_f32_16x16x32_f16(kf, qf[1][kk], s1[nb], 0, 0, 0);
      }
    }
    __builtin_amdgcn_s_setprio(0);
    half8v pa00, pa01, pa10, pa11;
    {
      float sum0 = 0.f, sum1 = 0.f;
      float e0[4][4], e1[4][4];
#pragma unroll
      for (int nb = 0; nb < 4; nb++)
#pragma unroll
        for (int r = 0; r < 4; r++) {
          float a = exp2f(s0[nb][r] * CEXP - 2.0f);
          float c = exp2f(s1[nb][r] * CEXP - 2.0f);
          e0[nb][r] = a; e1[nb][r] = c;
          sum0 += a; sum1 += c;
        }
      lsum[0] += sum0; lsum[1] += sum1;
#pragma unroll
      for (int r = 0; r < 4; r++) {
        pa00[r] = (half_t)e0[0][r]; pa00[r + 4] = (half_t)e0[1][r];
        pa01[r] = (half_t)e0[2][r]; pa01[r + 4] = (half_t)e0[3][r];
        pa10[r] = (half_t)e1[0][r]; pa10[r + 4] = (half_t)e1[1][r];
        pa11[r] = (half_t)e1[2][r]; pa11[r + 4] = (half_t)e1[3][r];
      }
    }
    __builtin_amdgcn_s_setprio(1);
#pragma unroll
    for (int cb = 0; cb < 8; cb++) {
      int row = cb * 16 + l15;
      int sw = (row & 7) << 4;
      half8v vf0 = *(const half8v*)(VsB + (row << 7) + ((l4 * 16) ^ sw));
      half8v vf1 = *(const half8v*)(VsB + (row << 7) + ((64 + l4 * 16) ^ sw));
      o[0][cb] = __builtin_amdgcn_mfma_f32_16x16x32_f16(pa00, vf0, o[0][cb], 0, 0, 0);
      o[0][cb] = __builtin_amdgcn_mfma_f32_16x16x32_f16(pa01, vf1, o[0][cb], 0, 0, 0);
      o[1][cb] = __builtin_amdgcn_mfma_f32_16x16x32_f16(pa10, vf0, o[1][cb], 0, 0, 0);
      o[1][cb] = __builtin_amdgcn_mfma_f32_16x16x32_f16(pa11, vf1, o[1][cb], 0, 0, 0);
    }
    __builtin_amdgcn_s_setprio(0);
    sel ^= 1;
  }
#undef STAGE
  float lreg[2];
#pragma unroll
  for (int t = 0; t < 2; t++) {
    float s = lsum[t];
    s += __shfl_xor(s, 16, 64);
    s += __shfl_xor(s, 32, 64);
    lreg[t] = s;
  }
#pragma unroll
  for (int t = 0; t < 2; t++) {
    float invq = 1.0f / lreg[t];
#pragma unroll
    for (int r = 0; r < 4; r++) {
      float inv = __shfl(invq, l4 * 4 + r, 64);
      int s = qb * 128 + wid * 32 + t * 16 + l4 * 4 + r;
#pragma unroll
      for (int cb = 0; cb < 8; cb++) {
        int col = h * HD + cb * 16 + l15;
        float val = o[t][cb][r] * inv;
        if (s >= S_TXT) val += ls * (float)ipout[(long)(s - S_TXT) * DM + col];
        ocomb[(long)s * DM + col] = (half_t)val;
      }
    }
  }
}

// ================================================================ host
extern "C" void kernel_launch(void* const* d_in, const int* in_sizes, int n_in,
                              void* d_out, int out_size, void* d_ws, size_t ws_size,
                              hipStream_t stream) {
  (void)in_sizes; (void)n_in; (void)out_size;
  const float* hs    = (const float*)d_in[0];
  const float* enc   = (const float*)d_in[1];
  const float* ipenc = (const float*)d_in[2];
  const float* lsc   = (const float*)d_in[3];
  const float* Wq  = (const float*)d_in[4];  const float* bq  = (const float*)d_in[5];
  const float* Wk  = (const float*)d_in[6];  const float* bk  = (const float*)d_in[7];
  const float* Wv  = (const float*)d_in[8];  const float* bv  = (const float*)d_in[9];
  const float* nqw = (const float*)d_in[10]; const float* nkw = (const float*)d_in[11];
  const float* Waq = (const float*)d_in[12]; const float* baq = (const float*)d_in[13];
  const float* Wak = (const float*)d_in[14]; const float* bak = (const float*)d_in[15];
  const float* Wav = (const float*)d_in[16]; const float* bav = (const float*)d_in[17];
  const float* naqw= (const float*)d_in[18]; const float* nakw= (const float*)d_in[19];
  const float* Wkip= (const float*)d_in[20]; const float* Wvip= (const float*)d_in[21];
  const float* Wo  = (const float*)d_in[22]; const float* bo  = (const float*)d_in[23];
  const float* Wao = (const float*)d_in[24]; const float* bao = (const float*)d_in[25];
  const float* cosb= (const float*)d_in[26]; const float* sinb= (const float*)d_in[27];

  const size_t WSZ = WSZC;
  const size_t HSZ = HSZC;
  const size_t ESZ = ESZC;
  const size_t CSZ = (size_t)NH * S_TOT * HD;
  const size_t REST = HSZ + ESZ + 3 * HSZ + 3 * ESZ + 3 * CSZ;
  const bool big = ws_size >= (6 * WSZ + REST) * sizeof(half_t);
  const int NSLOT = big ? 6 : 3;

  half_t* base = (half_t*)d_ws;
  half_t* Wsl   = base;
  half_t* hs_h  = Wsl + NSLOT * WSZ;
  half_t* enc_h = hs_h + HSZ;
  half_t* qkvr  = enc_h + ESZ;
  half_t* eqkv  = qkvr + 3 * HSZ;
  half_t* qcat  = eqkv + 3 * ESZ;
  half_t* kcat  = qcat + CSZ;
  half_t* vcatT = kcat + CSZ;

  half_t* q_raw = qkvr;
  half_t* k_raw = qkvr + HSZ;
  half_t* v_raw = qkvr + 2 * HSZ;
  half_t* eq_r  = eqkv;
  half_t* ek_r  = eqkv + ESZ;
  half_t* ev_r  = eqkv + 2 * ESZ;
  // aliases (stream-order safe)
  half_t* qnr   = hs_h;
  half_t* ipout = qkvr;
  half_t* ocomb = qkvr + HSZ;
  float*  ipk_raw = (float*)enc_h;
  float*  ipv_raw = ipk_raw + 4 * DM;
  half_t* ipk_h  = enc_h + 16 * DM;
  half_t* ipv_h  = ipk_h + 4 * DM;

  if (big) {
    cvt8_kernel<<<dim3(1024, 8), 256, 0, stream>>>(Wq, Wk, Wv, Waq, Wak, Wav,
                                                   hs, enc, Wsl, hs_h);
    gemm_qkv_kernel<<<1440, 256, 0, stream>>>(hs_h, enc_h, Wsl,
                                              bq, bk, bv, baq, bak, bav,
                                              q_raw, k_raw, v_raw, eq_r, ek_r, ev_r);
  } else {
    cvt_act_kernel<<<2048, 256, 0, stream>>>(hs, enc, hs_h);
    cvt3_kernel<<<dim3(1024, 3), 256, 0, stream>>>(Wq, Wk, Wv, Wsl, Wsl + WSZ, Wsl + 2 * WSZ, (int)WSZ);
    gemm3_kernel<16><<<1152, 256, 0, stream>>>(hs_h, Wsl, Wsl + WSZ, Wsl + 2 * WSZ,
                                               bq, bk, bv, q_raw, k_raw, v_raw);
    cvt3_kernel<<<dim3(1024, 3), 256, 0, stream>>>(Waq, Wak, Wav, Wsl, Wsl + WSZ, Wsl + 2 * WSZ, (int)WSZ);
    gemm3_kernel<4><<<288, 256, 0, stream>>>(enc_h, Wsl, Wsl + WSZ, Wsl + 2 * WSZ,
                                             baq, bak, bav, eq_r, ek_r, ev_r);
  }

  // ip path (merged k/v projections)
  ip_proj_kernel<<<dim3(768, 2), 256, 0, stream>>>(ipenc, Wkip, Wvip, ipk_raw, ipv_raw);
  ip_norm_kernel<<<192, 64, 0, stream>>>(ipk_raw, ipv_raw, ipk_h, ipv_h);

  // merged prep + vtrans (15360 prep blocks + 960 vtrans tiles)
  prep_vtrans_kernel<<<16320, 256, 0, stream>>>(q_raw, k_raw, eq_r, ek_r, ev_r, v_raw,
                                                nqw, nkw, naqw, nakw, cosb, sinb,
                                                qcat, kcat, qnr, vcatT);

  // ip attention (overwrites q_raw region)
  ip_attn_kernel<<<(NH * S_IMG) / 16, 256, 0, stream>>>(qnr, ipk_h, ipv_h, ipout);

  // main flash attention; big path embeds Wo/Wao convert into spare blocks
  if (big) {
    flash_kernel<<<480 + 512, 256, 0, stream>>>(qcat, kcat, vcatT, ipout, lsc, ocomb,
                                                Wo, Wao, Wsl, Wsl + WSZ);
  } else {
    flash_kernel<<<480, 256, 0, stream>>>(qcat, kcat, vcatT, ipout, lsc, ocomb,
                                          Wo, Wao, Wsl, Wsl + WSZ);
    cvt3_kernel<<<dim3(1024, 2), 256, 0, stream>>>(Wo, Wao, Wao, Wsl, Wsl + WSZ, Wsl + 2 * WSZ, (int)WSZ);
  }

  // output projections -> d_out f32 (weights in slots 0,1 either path)
  float* out_img = (float*)d_out;
  float* out_enc = (float*)d_out + (size_t)S_IMG * DM;
  gemm_out_kernel<<<480, 256, 0, stream>>>(ocomb, Wsl, Wsl + WSZ, bo, bao, out_img, out_enc);
}

// Round 21
// 493.504 us; speedup vs baseline: 1.0603x; 1.0171x over previous
//
#include <hip/hip_runtime.h>

typedef _Float16 half_t;
typedef _Float16 half2v __attribute__((ext_vector_type(2)));
typedef _Float16 half4v __attribute__((ext_vector_type(4)));
typedef _Float16 half8v __attribute__((ext_vector_type(8)));
typedef float    float4v __attribute__((ext_vector_type(4)));
typedef short    short8v __attribute__((ext_vector_type(8)));

#define S_IMG 2048
#define S_TXT 512
#define S_TOT 2560
#define NH    24
#define HD    128
#define DM    3072
#define WSZC  9437184L   // DM*DM
#define HSZC  6291456L   // S_IMG*DM
#define ESZC  1572864L   // S_TXT*DM

// async global->LDS, 16B per lane, wave-uniform LDS base (+ lane*16 by HW)
__device__ __forceinline__ void gload16(const void* g, void* l) {
  __builtin_amdgcn_global_load_lds(
      (const __attribute__((address_space(1))) unsigned int*)g,
      (__attribute__((address_space(3))) unsigned int*)l, 16, 0, 0);
}

__device__ __forceinline__ void cvt8span(const float* s, half_t* d, long i) {
  float4v v0 = *(const float4v*)(s + i);
  float4v v1 = *(const float4v*)(s + i + 4);
  half8v h;
  h[0] = (half_t)v0[0]; h[1] = (half_t)v0[1]; h[2] = (half_t)v0[2]; h[3] = (half_t)v0[3];
  h[4] = (half_t)v1[0]; h[5] = (half_t)v1[1]; h[6] = (half_t)v1[2]; h[7] = (half_t)v1[3];
  *(half8v*)(d + i) = h;
}

// ---------------------------------------------------------------- activations -> f16 (merged)
__global__ void cvt_act_kernel(const float* __restrict__ hs, const float* __restrict__ enc,
                               half_t* __restrict__ d) {
  const long TOT = HSZC + ESZC;
  long i = ((long)blockIdx.x * 256 + threadIdx.x) * 8;
  long stride = (long)gridDim.x * 256 * 8;
  for (; i < TOT; i += stride) {
    const float* s = i < HSZC ? hs + i : enc + (i - HSZC);
    cvt8span(s, d + i, 0);
  }
}

// merged 2/3-region weight convert; region = blockIdx.y (fallback path)
__global__ void cvt3_kernel(const float* __restrict__ s0, const float* __restrict__ s1,
                            const float* __restrict__ s2,
                            half_t* __restrict__ d0, half_t* __restrict__ d1,
                            half_t* __restrict__ d2, int n) {
  const float* s = blockIdx.y == 0 ? s0 : (blockIdx.y == 1 ? s1 : s2);
  half_t* d = blockIdx.y == 0 ? d0 : (blockIdx.y == 1 ? d1 : d2);
  long i = ((long)blockIdx.x * 256 + threadIdx.x) * 8;
  long stride = (long)gridDim.x * 256 * 8;
  for (; i < n; i += stride) cvt8span(s, d, i);
}

// 8-region convert: y=0..5 -> weights into W6 slots; y=6 hs; y=7 enc (big path)
__global__ void cvt8_kernel(const float* w0, const float* w1, const float* w2,
                            const float* w3, const float* w4, const float* w5,
                            const float* hs, const float* enc,
                            half_t* __restrict__ W6, half_t* __restrict__ hs_h) {
  int y = blockIdx.y;
  const float* s;
  half_t* d;
  long n;
  if (y < 6) {
    s = y == 0 ? w0 : y == 1 ? w1 : y == 2 ? w2 : y == 3 ? w3 : y == 4 ? w4 : w5;
    d = W6 + (long)y * WSZC;
    n = WSZC;
  } else if (y == 6) { s = hs; d = hs_h; n = HSZC; }
  else               { s = enc; d = hs_h + HSZC; n = ESZC; }
  long i = ((long)blockIdx.x * 256 + threadIdx.x) * 8;
  long stride = (long)gridDim.x * 256 * 8;
  for (; i < n; i += stride) cvt8span(s, d, i);
}

// ------------------------------------------------ ip projection body (shared)
__device__ __forceinline__ void ip_proj_body(const float* __restrict__ x,
                                             const float* __restrict__ W,
                                             float* __restrict__ out, int bx) {
  int n = bx * 4 + (threadIdx.x >> 6);
  int l = threadIdx.x & 63;
  const float* wr = W + (long)n * DM;
  float acc[4] = {0.f, 0.f, 0.f, 0.f};
  for (int k = l * 4; k < DM; k += 256) {
    float4v wv = *(const float4v*)(wr + k);
#pragma unroll
    for (int p = 0; p < 4; p++) {
      float4v xv = *(const float4v*)(x + p * DM + k);
      acc[p] += wv[0] * xv[0] + wv[1] * xv[1] + wv[2] * xv[2] + wv[3] * xv[3];
    }
  }
#pragma unroll
  for (int off = 32; off; off >>= 1)
#pragma unroll
    for (int p = 0; p < 4; p++) acc[p] += __shfl_xor(acc[p], off, 64);
  if (l == 0)
#pragma unroll
    for (int p = 0; p < 4; p++) out[p * DM + n] = acc[p];
}

// ------------------------------------------------ ip k-norm body (task in [0,192))
__device__ __forceinline__ void ip_norm_body(const float* __restrict__ kr,
                                             const float* __restrict__ vr,
                                             half_t* __restrict__ kh,
                                             half_t* __restrict__ vh, int t, int l) {
  int d = l * 2;
  if (t < 96) {
    int base = (t / 24) * DM + (t % 24) * HD;
    float x0 = kr[base + d], x1 = kr[base + d + 1];
    float ss = x0 * x0 + x1 * x1;
#pragma unroll
    for (int off = 32; off; off >>= 1) ss += __shfl_xor(ss, off, 64);
    float r = rsqrtf(ss * (1.0f / HD) + 1e-5f);
    kh[base + d] = (half_t)(x0 * r);
    kh[base + d + 1] = (half_t)(x1 * r);
  } else {
    int t2 = t - 96;
    int base = (t2 / 24) * DM + (t2 % 24) * HD;
    vh[base + d] = (half_t)vr[base + d];
    vh[base + d + 1] = (half_t)vr[base + d + 1];
  }
}

// ------------------------------------------------ 128x128 GEMM tile body
// 2-buffer 1-ahead pipeline: vmcnt(0) -> barrier -> stage(t+1) -> compute(t).
// 64B-row XOR swizzle (slot ^= (row>>1)&3).
template <typename OUT>
__device__ __forceinline__ void gemm_tile(half_t* As, half_t* Bs,  // each 2*4096 halves
                                          const half_t* __restrict__ A,
                                          const half_t* __restrict__ Bt,
                                          const float* __restrict__ bias,
                                          OUT* __restrict__ C, int bm, int bn) {
  const int K = DM, N = DM;
  const int tid = threadIdx.x, wid = tid >> 6, l = tid & 63;
  const int wm = (wid >> 1) * 64, wn = (wid & 1) * 64;
  const int l15 = l & 15, l4 = l >> 4;
  float4v acc[4][4] = {};

  const int scol = ((l & 3) ^ ((l >> 3) & 3)) * 8;
  const half_t* ga = A + (long)(bm + wid * 32 + (l >> 2)) * K + scol;
  const half_t* gb = Bt + (long)(bn + wid * 32 + (l >> 2)) * K + scol;
  const long rowstep = 16l * K;

#define GSTAGE(T, SEL)                                                        \
  {                                                                           \
    char* a_d = (char*)As + (SEL) * 8192 + wid * 2048;                        \
    char* b_d = (char*)Bs + (SEL) * 8192 + wid * 2048;                        \
    int k0 = (T) * 32;                                                        \
    gload16(ga + k0, a_d);                                                    \
    gload16(ga + rowstep + k0, a_d + 1024);                                   \
    gload16(gb + k0, b_d);                                                    \
    gload16(gb + rowstep + k0, b_d + 1024);                                   \
  }

  GSTAGE(0, 0);

  const int NT = K / 32;  // 96
  const int cofs = (l4 * 16) ^ (((l15 >> 1) & 3) << 4);  // swizzled byte-in-row
  int sel = 0;
  for (int t = 0; t < NT; t++) {
    asm volatile("s_waitcnt vmcnt(0)" ::: "memory");
    __builtin_amdgcn_s_barrier();
    __builtin_amdgcn_sched_barrier(0);
    if (t + 1 < NT) GSTAGE(t + 1, sel ^ 1);
    __builtin_amdgcn_sched_barrier(0);
    const char* AsB = (const char*)As + sel * 8192;
    const char* BsB = (const char*)Bs + sel * 8192;
    half8v af[4], bf[4];
#pragma unroll
    for (int i = 0; i < 4; i++)
      af[i] = *(const half8v*)(AsB + (wm + i * 16 + l15) * 64 + cofs);
#pragma unroll
    for (int j = 0; j < 4; j++)
      bf[j] = *(const half8v*)(BsB + (wn + j * 16 + l15) * 64 + cofs);
    __builtin_amdgcn_s_setprio(1);
#pragma unroll
    for (int i = 0; i < 4; i++)
#pragma unroll
      for (int j = 0; j < 4; j++)
        acc[i][j] = __builtin_amdgcn_mfma_f32_16x16x32_f16(af[i], bf[j], acc[i][j], 0, 0, 0);
    __builtin_amdgcn_s_setprio(0);
    sel ^= 1;
  }
#undef GSTAGE
#pragma unroll
  for (int i = 0; i < 4; i++)
#pragma unroll
    for (int j = 0; j < 4; j++) {
      int row = bm + wm + i * 16 + l4 * 4;
      int col = bn + wn + j * 16 + l15;
      float bv = bias ? bias[col] : 0.0f;
#pragma unroll
      for (int r = 0; r < 4; r++) {
        float v = acc[i][j][r] + bv;
        C[(long)(row + r) * N + col] = (OUT)v;
      }
    }
}

// merged img+enc QKV GEMM (1440 blocks, XCD swizzle 8x180) + embedded ip_proj
// (blocks 1440..2975: 1536 ip projection blocks, inputs independent of GEMM)
__global__ __launch_bounds__(256) void gemm_qkv_kernel(
    const half_t* __restrict__ hs_h, const half_t* __restrict__ enc_h,
    const half_t* __restrict__ W6,
    const float* bq, const float* bk, const float* bv,
    const float* baq, const float* bak, const float* bav,
    half_t* q_raw, half_t* k_raw, half_t* v_raw,
    half_t* eq_r, half_t* ek_r, half_t* ev_r,
    const float* __restrict__ ipenc,
    const float* __restrict__ Wkip, const float* __restrict__ Wvip,
    float* __restrict__ ipk_raw, float* __restrict__ ipv_raw) {
  __shared__ half_t As[2 * 4096];
  __shared__ half_t Bs[2 * 4096];
  int b = blockIdx.x;
  if (b >= 1440) {                      // embedded ip projection blocks
    int b2 = b - 1440;                  // 0..1535
    const float* W = b2 >= 768 ? Wvip : Wkip;
    float* out = b2 >= 768 ? ipv_raw : ipk_raw;
    int bx = b2 >= 768 ? b2 - 768 : b2;   // FIX: 768 is not a pow2; no mask
    ip_proj_body(ipenc, W, out, bx);
    return;
  }
  int wg = (b & 7) * 180 + (b >> 3);
  const half_t* A;
  const half_t* Bt;
  const float* bias;
  half_t* C;
  int bm, bn;
  if (wg < 1152) {
    int col = wg / 16, row = wg % 16;
    int sel = col / 24;
    A = hs_h; bm = row * 128; bn = (col % 24) * 128;
    Bt = W6 + (long)sel * WSZC;
    bias = sel == 0 ? bq : (sel == 1 ? bk : bv);
    C = sel == 0 ? q_raw : (sel == 1 ? k_raw : v_raw);
  } else {
    int w2 = wg - 1152;
    int col = w2 / 4, row = w2 % 4;
    int sel = col / 24;
    A = enc_h; bm = row * 128; bn = (col % 24) * 128;
    Bt = W6 + (long)(3 + sel) * WSZC;
    bias = sel == 0 ? baq : (sel == 1 ? bak : bav);
    C = sel == 0 ? eq_r : (sel == 1 ? ek_r : ev_r);
  }
  gemm_tile<half_t>(As, Bs, A, Bt, bias, C, bm, bn);
}

// fallback: fused triple-GEMM, 1D XCD-swizzled grid; NROW row-blocks, 72 col-blocks
template <int NROW>
__global__ __launch_bounds__(256) void gemm3_kernel(const half_t* __restrict__ A,
                                                    const half_t* __restrict__ W0,
                                                    const half_t* __restrict__ W1,
                                                    const half_t* __restrict__ W2,
                                                    const float* b0, const float* b1, const float* b2,
                                                    half_t* O0, half_t* O1, half_t* O2) {
  __shared__ half_t As[2 * 4096];
  __shared__ half_t Bs[2 * 4096];
  int b = blockIdx.x;
  int q = (72 * NROW) >> 3;
  int wg = (b & 7) * q + (b >> 3);
  int col = wg / NROW, row = wg % NROW;
  int sel = col / 24;
  const half_t* Bt = sel == 0 ? W0 : (sel == 1 ? W1 : W2);
  const float* bias = sel == 0 ? b0 : (sel == 1 ? b1 : b2);
  half_t* C = sel == 0 ? O0 : (sel == 1 ? O1 : O2);
  gemm_tile<half_t>(As, Bs, A, Bt, bias, C, row * 128, (col % 24) * 128);
}

// fused output projections; 1D grid 480 = 8 x 60; r<16 img, r>=16 enc
__global__ __launch_bounds__(256) void gemm_out_kernel(const half_t* __restrict__ ocomb,
                                                       const half_t* __restrict__ Wo_h,
                                                       const half_t* __restrict__ Wao_h,
                                                       const float* bo, const float* bao,
                                                       float* out_img, float* out_enc) {
  __shared__ half_t As[2 * 4096];
  __shared__ half_t Bs[2 * 4096];
  int b = blockIdx.x;
  int wg = (b & 7) * 60 + (b >> 3);
  int col = wg / 20, r = wg % 20;
  bool enc = r >= 16;
  const half_t* A = enc ? ocomb : ocomb + (long)S_TXT * DM;
  int bm = (enc ? (r - 16) : r) * 128;
  gemm_tile<float>(As, Bs, A, enc ? Wao_h : Wo_h, enc ? bao : bo,
                   enc ? out_enc : out_img, bm, col * 128);
}

// ------------------------------------------------ standalone ip kernels (fallback path)
__global__ __launch_bounds__(256) void ip_proj_kernel(const float* __restrict__ x,
                                                      const float* __restrict__ Wk_ip,
                                                      const float* __restrict__ Wv_ip,
                                                      float* __restrict__ outk,
                                                      float* __restrict__ outv) {
  const float* W = blockIdx.y ? Wv_ip : Wk_ip;
  float* out = blockIdx.y ? outv : outk;
  ip_proj_body(x, W, out, blockIdx.x);
}

__global__ void ip_norm_kernel(const float* __restrict__ kr, const float* __restrict__ vr,
                               half_t* __restrict__ kh, half_t* __restrict__ vh) {
  ip_norm_body(kr, vr, kh, vh, blockIdx.x, threadIdx.x);
}

// ------------------------------------------------ merged prep (rmsnorm+rope+concat) + vtrans
// blocks < 15360: prep rows; 15360..16319: V transpose+pi-permute; >=16320: ip_norm (48 blocks)
__global__ __launch_bounds__(256) void prep_vtrans_kernel(
    const half_t* __restrict__ qraw, const half_t* __restrict__ kraw,
    const half_t* __restrict__ eq, const half_t* __restrict__ ek,
    const half_t* __restrict__ ev, const half_t* __restrict__ vraw,
    const float* __restrict__ nqw, const float* __restrict__ nkw,
    const float* __restrict__ naqw, const float* __restrict__ nakw,
    const float* __restrict__ cosb, const float* __restrict__ sinb,
    half_t* __restrict__ qcat, half_t* __restrict__ kcat, half_t* __restrict__ qnr,
    half_t* __restrict__ vcatT,
    const float* __restrict__ ipk_raw, const float* __restrict__ ipv_raw,
    half_t* __restrict__ ipk_h, half_t* __restrict__ ipv_h) {
  __shared__ half_t T[64][136];
  if (blockIdx.x >= 16320) {            // embedded ip_norm: 48 blocks x 4 tasks
    int task = (blockIdx.x - 16320) * 4 + (threadIdx.x >> 6);
    ip_norm_body(ipk_raw, ipv_raw, ipk_h, ipv_h, task, threadIdx.x & 63);
    return;
  }
  if (blockIdx.x < 15360) {
    int task = blockIdx.x * 4 + (threadIdx.x >> 6);
    int l = threadIdx.x & 63;
    int s = task / NH, h = task - (task / NH) * NH;
    int d = l * 2;
    const half_t *qs, *ks;
    const float *wq, *wk;
    if (s < S_TXT) {
      long base = (long)s * DM + h * HD;
      qs = eq + base; ks = ek + base;
      wq = naqw; wk = nakw;
    } else {
      long base = (long)(s - S_TXT) * DM + h * HD;
      qs = qraw + base; ks = kraw + base;
      wq = nqw; wk = nkw;
    }
    half2v qv = *(const half2v*)(qs + d);
    half2v kv = *(const half2v*)(ks + d);
    float q0 = (float)qv[0], q1 = (float)qv[1];
    float k0 = (float)kv[0], k1 = (float)kv[1];
    float ssq = q0 * q0 + q1 * q1;
    float ssk = k0 * k0 + k1 * k1;
#pragma unroll
    for (int off = 32; off; off >>= 1) {
      ssq += __shfl_xor(ssq, off, 64);
      ssk += __shfl_xor(ssk, off, 64);
    }
    float rq = rsqrtf(ssq * (1.0f / HD) + 1e-6f);
    float rk = rsqrtf(ssk * (1.0f / HD) + 1e-6f);
    float qn0 = q0 * rq * wq[d], qn1 = q1 * rq * wq[d + 1];
    float kn0 = k0 * rk * wk[d], kn1 = k1 * rk * wk[d + 1];
    if (s >= S_TXT) {
      half2v o; o[0] = (half_t)qn0; o[1] = (half_t)qn1;
      *(half2v*)(qnr + ((long)h * S_IMG + (s - S_TXT)) * HD + d) = o;
    }
    float c0 = cosb[s * HD + d], c1 = cosb[s * HD + d + 1];
    float s0 = sinb[s * HD + d], s1 = sinb[s * HD + d + 1];
    float qo0 = qn0 * c0 - qn1 * s0, qo1 = qn1 * c1 + qn0 * s1;
    float ko0 = kn0 * c0 - kn1 * s0, ko1 = kn1 * c1 + kn0 * s1;
    long ci = ((long)h * S_TOT + s) * HD + d;
    half2v oq; oq[0] = (half_t)qo0; oq[1] = (half_t)qo1;
    half2v ok; ok[0] = (half_t)ko0; ok[1] = (half_t)ko1;
    *(half2v*)(qcat + ci) = oq;
    *(half2v*)(kcat + ci) = ok;
  } else {
    int b2 = blockIdx.x - 15360;       // 960 tiles = 24 heads x 40 s-blocks
    int h = b2 / 40, sb = (b2 % 40) * 64;
    int t = threadIdx.x;
#pragma unroll
    for (int i = 0; i < 4; i++) {
      int c = t + i * 256;
      int row = c >> 4, col = (c & 15) * 8;
      int s = sb + row;
      const half_t* src = (s < S_TXT) ? ev + (long)s * DM + h * HD + col
                                      : vraw + (long)(s - S_TXT) * DM + h * HD + col;
      *(half8v*)&T[row][col] = *(const half8v*)src;
    }
    __syncthreads();
#pragma unroll
    for (int i = 0; i < 4; i++) {
      int c = t + i * 256;
      int d = c >> 3, sc = (c & 7) * 8;
      half8v v;
#pragma unroll
      for (int j = 0; j < 8; j++) v[j] = T[sc + j][d];
      // pi^{-1}: dst_b4 = s_b3, dst_b3 = s_b2, dst_b2 = s_b4 (3-cycle)
      int base = (sc & 32) | ((sc & 8) << 1) | ((sc & 16) >> 2);
      half_t* dst = vcatT + ((long)h * HD + d) * S_TOT + sb;
      half4v q0; q0[0] = v[0]; q0[1] = v[1]; q0[2] = v[2]; q0[3] = v[3];
      half4v q1; q1[0] = v[4]; q1[1] = v[5]; q1[2] = v[6]; q1[3] = v[7];
      *(half4v*)(dst + base) = q0;
      *(half4v*)(dst + base + 8) = q1;
    }
  }
}

// ------------------------------------------------ ip attention (4 keys), 8 halves/lane
__global__ __launch_bounds__(256) void ip_attn_kernel(const half_t* __restrict__ qnr,
                                                      const half_t* __restrict__ kh,
                                                      const half_t* __restrict__ vh,
                                                      half_t* __restrict__ ipout) {
  int tid = threadIdx.x;
  int task = blockIdx.x * 16 + (tid >> 4);
  int l16 = tid & 15;
  int h = task >> 11;
  int s = task & 2047;
  int d = l16 * 8;
  half8v qv = *(const half8v*)(qnr + ((long)h * S_IMG + s) * HD + d);
  float sc[4];
#pragma unroll
  for (int p = 0; p < 4; p++) {
    half8v kv = *(const half8v*)(kh + p * DM + h * HD + d);
    float a = 0.f;
#pragma unroll
    for (int j = 0; j < 8; j++) a += (float)qv[j] * (float)kv[j];
    sc[p] = a;
  }
#pragma unroll
  for (int off = 8; off; off >>= 1)
#pragma unroll
    for (int p = 0; p < 4; p++) sc[p] += __shfl_xor(sc[p], off, 16);
  float m = fmaxf(fmaxf(sc[0], sc[1]), fmaxf(sc[2], sc[3]));
  float e[4], sum = 0.f;
#pragma unroll
  for (int p = 0; p < 4; p++) { e[p] = __expf((sc[p] - m) * 0.088388347648318447f); sum += e[p]; }
  float inv = 1.0f / sum;
  float o[8] = {};
#pragma unroll
  for (int p = 0; p < 4; p++) {
    half8v vv = *(const half8v*)(vh + p * DM + h * HD + d);
#pragma unroll
    for (int j = 0; j < 8; j++) o[j] += e[p] * (float)vv[j];
  }
  half8v ov;
#pragma unroll
  for (int j = 0; j < 8; j++) ov[j] = (half_t)(o[j] * inv);
  *(half8v*)(ipout + (long)s * DM + h * HD + d) = ov;
}

// ------------------------------------------------ flash attention, KVBLK=64, 2-buf 1-ahead
// Blocks >= 480 convert Wo/Wao f32->f16 into dead weight slots (hidden under flash).
__global__ __launch_bounds__(256, 2) void flash_kernel(const half_t* __restrict__ qcat,
                                                       const half_t* __restrict__ kcat,
                                                       const half_t* __restrict__ vcatT,
                                                       const half_t* __restrict__ ipout,
                                                       const float* __restrict__ lsp,
                                                       half_t* __restrict__ ocomb,
                                                       const float* __restrict__ WoF,
                                                       const float* __restrict__ WaoF,
                                                       half_t* __restrict__ w0d,
                                                       half_t* __restrict__ w1d) {
  __shared__ half_t Ks[2 * 64 * 128];  // 32 KB, rows 256B XOR-swizzled
  __shared__ half_t Vs[2 * 128 * 64];  // 32 KB, rows 128B XOR-swizzled
  if (blockIdx.x >= 480) {             // embedded weight-convert blocks
    int cb = blockIdx.x - 480;
    long i = ((long)cb * 256 + threadIdx.x) * 8;
    long stride = (long)(gridDim.x - 480) * 256 * 8;
    for (; i < 2 * WSZC; i += stride) {
      if (i < WSZC) cvt8span(WoF, w0d, i);
      else          cvt8span(WaoF, w1d, i - WSZC);
    }
    return;
  }
  int b = blockIdx.x;
  int wg = (b & 7) * 60 + (b >> 3);    // bijective XCD swizzle (480 = 8x60)
  const int h = wg / 20, qb = wg % 20;
  const int tid = threadIdx.x, wid = tid >> 6, l = tid & 63;
  const int l15 = l & 15, l4 = l >> 4;
  const float CEXP = 0.12754137969983614f;  // (1/sqrt(128)) * log2(e)

  half8v qf[2][4];
#pragma unroll
  for (int t = 0; t < 2; t++) {
    int qrow = qb * 128 + wid * 32 + t * 16 + l15;
    const half_t* qp = qcat + ((long)h * S_TOT + qrow) * HD;
#pragma unroll
    for (int kk = 0; kk < 4; kk++) qf[t][kk] = *(const half8v*)(qp + kk * 32 + l4 * 8);
  }
  float4v o[2][8] = {};
  float lsum[2] = {0.f, 0.f};
  const float ls = lsp[0];

  const char* kb = (const char*)(kcat + (long)h * S_TOT * HD);
  const char* vb = (const char*)(vcatT + (long)h * HD * S_TOT);
  int kof[4];
  long vof[4];
#pragma unroll
  for (int c = 0; c < 4; c++) {
    int L = c * 4096 + tid * 16;
    kof[c] = L ^ (((L >> 8) & 7) << 4);
    int vrow = L >> 7;
    vof[c] = (long)vrow * (S_TOT * 2) + ((L & 127) ^ ((vrow & 7) << 4));
  }

#define STAGE(KT, SEL)                                                        \
  {                                                                           \
    char* kd = (char*)Ks + (SEL) * 16384 + wid * 1024;                        \
    char* vd = (char*)Vs + (SEL) * 16384 + wid * 1024;                        \
    _Pragma("unroll") for (int c = 0; c < 4; c++) {                           \
      gload16(kb + (long)(KT) * 256 + kof[c], kd + c * 4096);                 \
      gload16(vb + vof[c] + (KT) * 2, vd + c * 4096);                         \
    }                                                                         \
  }

  STAGE(0, 0);

  const int NT = S_TOT / 64;  // 40
  int sel = 0;
  for (int it = 0; it < NT; it++) {
    asm volatile("s_waitcnt vmcnt(0)" ::: "memory");
    __builtin_amdgcn_s_barrier();
    __builtin_amdgcn_sched_barrier(0);
    if (it + 1 < NT) STAGE((it + 1) * 64, sel ^ 1);

    const char* KsB = (const char*)Ks + sel * 16384;
    const char* VsB = (const char*)Vs + sel * 16384;

    float4v s0[4] = {}, s1[4] = {};
    __builtin_amdgcn_s_setprio(1);
#pragma unroll
    for (int nb = 0; nb < 4; nb++) {
      int krow = nb * 16 + l15;
      int rb = krow << 8;
      int sw = (krow & 7) << 4;
#pragma unroll
      for (int kk = 0; kk < 4; kk++) {
        half8v kf = *(const half8v*)(KsB + rb + ((kk * 64 + l4 * 16) ^ sw));
        s0[nb] = __builtin_amdgcn_mfma_f32_16x16x32_f16(kf, qf[0][kk], s0[nb], 0, 0, 0);
        s1[nb] = __builtin_amdgcn_mfma_f32_16x16x32_f16(kf, qf[1][kk], s1[nb], 0, 0, 0);
      }
    }
    __builtin_amdgcn_s_setprio(0);
    half8v pa00, pa01, pa10, pa11;
    {
      float sum0 = 0.f, sum1 = 0.f;
      float e0[4][4], e1[4][4];
#pragma unroll
      for (int nb = 0; nb < 4; nb++)
#pragma unroll
        for (int r = 0; r < 4; r++) {
          float a = exp2f(s0[nb][r] * CEXP - 2.0f);
          float c = exp2f(s1[nb][r] * CEXP - 2.0f);
          e0[nb][r] = a; e1[nb][r] = c;
          sum0 += a; sum1 += c;
        }
      lsum[0] += sum0; lsum[1] += sum1;
#pragma unroll
      for (int r = 0; r < 4; r++) {
        pa00[r] = (half_t)e0[0][r]; pa00[r + 4] = (half_t)e0[1][r];
        pa01[r] = (half_t)e0[2][r]; pa01[r + 4] = (half_t)e0[3][r];
        pa10[r] = (half_t)e1[0][r]; pa10[r + 4] = (half_t)e1[1][r];
        pa11[r] = (half_t)e1[2][r]; pa11[r + 4] = (half_t)e1[3][r];
      }
    }
    __builtin_amdgcn_s_setprio(1);
#pragma unroll
    for (int cb = 0; cb < 8; cb++) {
      int row = cb * 16 + l15;
      int sw = (row & 7) << 4;
      half8v vf0 = *(const half8v*)(VsB + (row << 7) + ((l4 * 16) ^ sw));
      half8v vf1 = *(const half8v*)(VsB + (row << 7) + ((64 + l4 * 16) ^ sw));
      o[0][cb] = __builtin_amdgcn_mfma_f32_16x16x32_f16(pa00, vf0, o[0][cb], 0, 0, 0);
      o[0][cb] = __builtin_amdgcn_mfma_f32_16x16x32_f16(pa01, vf1, o[0][cb], 0, 0, 0);
      o[1][cb] = __builtin_amdgcn_mfma_f32_16x16x32_f16(pa10, vf0, o[1][cb], 0, 0, 0);
      o[1][cb] = __builtin_amdgcn_mfma_f32_16x16x32_f16(pa11, vf1, o[1][cb], 0, 0, 0);
    }
    __builtin_amdgcn_s_setprio(0);
    sel ^= 1;
  }
#undef STAGE
  float lreg[2];
#pragma unroll
  for (int t = 0; t < 2; t++) {
    float s = lsum[t];
    s += __shfl_xor(s, 16, 64);
    s += __shfl_xor(s, 32, 64);
    lreg[t] = s;
  }
#pragma unroll
  for (int t = 0; t < 2; t++) {
    float invq = 1.0f / lreg[t];
#pragma unroll
    for (int r = 0; r < 4; r++) {
      float inv = __shfl(invq, l4 * 4 + r, 64);
      int s = qb * 128 + wid * 32 + t * 16 + l4 * 4 + r;
#pragma unroll
      for (int cb = 0; cb < 8; cb++) {
        int col = h * HD + cb * 16 + l15;
        float val = o[t][cb][r] * inv;
        if (s >= S_TXT) val += ls * (float)ipout[(long)(s - S_TXT) * DM + col];
        ocomb[(long)s * DM + col] = (half_t)val;
      }
    }
  }
}

// ================================================================ host
extern "C" void kernel_launch(void* const* d_in, const int* in_sizes, int n_in,
                              void* d_out, int out_size, void* d_ws, size_t ws_size,
                              hipStream_t stream) {
  (void)in_sizes; (void)n_in; (void)out_size;
  const float* hs    = (const float*)d_in[0];
  const float* enc   = (const float*)d_in[1];
  const float* ipenc = (const float*)d_in[2];
  const float* lsc   = (const float*)d_in[3];
  const float* Wq  = (const float*)d_in[4];  const float* bq  = (const float*)d_in[5];
  const float* Wk  = (const float*)d_in[6];  const float* bk  = (const float*)d_in[7];
  const float* Wv  = (const float*)d_in[8];  const float* bv  = (const float*)d_in[9];
  const float* nqw = (const float*)d_in[10]; const float* nkw = (const float*)d_in[11];
  const float* Waq = (const float*)d_in[12]; const float* baq = (const float*)d_in[13];
  const float* Wak = (const float*)d_in[14]; const float* bak = (const float*)d_in[15];
  const float* Wav = (const float*)d_in[16]; const float* bav = (const float*)d_in[17];
  const float* naqw= (const float*)d_in[18]; const float* nakw= (const float*)d_in[19];
  const float* Wkip= (const float*)d_in[20]; const float* Wvip= (const float*)d_in[21];
  const float* Wo  = (const float*)d_in[22]; const float* bo  = (const float*)d_in[23];
  const float* Wao = (const float*)d_in[24]; const float* bao = (const float*)d_in[25];
  const float* cosb= (const float*)d_in[26]; const float* sinb= (const float*)d_in[27];

  const size_t WSZ = WSZC;
  const size_t HSZ = HSZC;
  const size_t ESZ = ESZC;
  const size_t CSZ = (size_t)NH * S_TOT * HD;
  const size_t IPX = 4 * DM;                      // ip vector size (elements)
  const size_t EXTRA = 2 * (2 * IPX) + 2 * IPX;   // in half_t units
  const size_t REST = HSZ + ESZ + 3 * HSZ + 3 * ESZ + 3 * CSZ;
  const bool big = ws_size >= (6 * WSZ + REST + EXTRA) * sizeof(half_t);
  const int NSLOT = big ? 6 : 3;

  half_t* base = (half_t*)d_ws;
  half_t* Wsl   = base;
  half_t* hs_h  = Wsl + NSLOT * WSZ;
  half_t* enc_h = hs_h + HSZ;
  half_t* qkvr  = enc_h + ESZ;
  half_t* eqkv  = qkvr + 3 * HSZ;
  half_t* qcat  = eqkv + 3 * ESZ;
  half_t* kcat  = qcat + CSZ;
  half_t* vcatT = kcat + CSZ;
  half_t* tail  = vcatT + CSZ;          // big-path ip buffers

  half_t* q_raw = qkvr;
  half_t* k_raw = qkvr + HSZ;
  half_t* v_raw = qkvr + 2 * HSZ;
  half_t* eq_r  = eqkv;
  half_t* ek_r  = eqkv + ESZ;
  half_t* ev_r  = eqkv + 2 * ESZ;
  // aliases (stream-order safe)
  half_t* qnr   = hs_h;
  half_t* ipout = qkvr;
  half_t* ocomb = qkvr + HSZ;

  float*  ipk_raw;
  float*  ipv_raw;
  half_t* ipk_h;
  half_t* ipv_h;
  if (big) {
    ipk_raw = (float*)tail;
    ipv_raw = ipk_raw + IPX;
    ipk_h   = tail + 4 * IPX;
    ipv_h   = ipk_h + IPX;
  } else {
    ipk_raw = (float*)enc_h;
    ipv_raw = ipk_raw + IPX;
    ipk_h   = enc_h + 4 * IPX;
    ipv_h   = ipk_h + IPX;
  }

  if (big) {
    cvt8_kernel<<<dim3(1024, 8), 256, 0, stream>>>(Wq, Wk, Wv, Waq, Wak, Wav,
                                                   hs, enc, Wsl, hs_h);
    // QKV GEMM + embedded ip projections (independent inputs, HBM hidden under compute)
    gemm_qkv_kernel<<<1440 + 1536, 256, 0, stream>>>(hs_h, enc_h, Wsl,
                                                     bq, bk, bv, baq, bak, bav,
                                                     q_raw, k_raw, v_raw, eq_r, ek_r, ev_r,
                                                     ipenc, Wkip, Wvip, ipk_raw, ipv_raw);
    // prep + vtrans + embedded ip_norm
    prep_vtrans_kernel<<<16320 + 48, 256, 0, stream>>>(q_raw, k_raw, eq_r, ek_r, ev_r, v_raw,
                                                       nqw, nkw, naqw, nakw, cosb, sinb,
                                                       qcat, kcat, qnr, vcatT,
                                                       ipk_raw, ipv_raw, ipk_h, ipv_h);
  } else {
    cvt_act_kernel<<<2048, 256, 0, stream>>>(hs, enc, hs_h);
    cvt3_kernel<<<dim3(1024, 3), 256, 0, stream>>>(Wq, Wk, Wv, Wsl, Wsl + WSZ, Wsl + 2 * WSZ, (int)WSZ);
    gemm3_kernel<16><<<1152, 256, 0, stream>>>(hs_h, Wsl, Wsl + WSZ, Wsl + 2 * WSZ,
                                               bq, bk, bv, q_raw, k_raw, v_raw);
    cvt3_kernel<<<dim3(1024, 3), 256, 0, stream>>>(Waq, Wak, Wav, Wsl, Wsl + WSZ, Wsl + 2 * WSZ, (int)WSZ);
    gemm3_kernel<4><<<288, 256, 0, stream>>>(enc_h, Wsl, Wsl + WSZ, Wsl + 2 * WSZ,
                                             baq, bak, bav, eq_r, ek_r, ev_r);
    ip_proj_kernel<<<dim3(768, 2), 256, 0, stream>>>(ipenc, Wkip, Wvip, ipk_raw, ipv_raw);
    ip_norm_kernel<<<192, 64, 0, stream>>>(ipk_raw, ipv_raw, ipk_h, ipv_h);
    prep_vtrans_kernel<<<16320, 256, 0, stream>>>(q_raw, k_raw, eq_r, ek_r, ev_r, v_raw,
                                                  nqw, nkw, naqw, nakw, cosb, sinb,
                                                  qcat, kcat, qnr, vcatT,
                                                  ipk_raw, ipv_raw, ipk_h, ipv_h);
  }

  // ip attention (overwrites q_raw region)
  ip_attn_kernel<<<(NH * S_IMG) / 16, 256, 0, stream>>>(qnr, ipk_h, ipv_h, ipout);

  // main flash attention; embeds Wo/Wao convert into spare blocks (big path)
  if (big) {
    flash_kernel<<<480 + 512, 256, 0, stream>>>(qcat, kcat, vcatT, ipout, lsc, ocomb,
                                                Wo, Wao, Wsl, Wsl + WSZ);
  } else {
    flash_kernel<<<480, 256, 0, stream>>>(qcat, kcat, vcatT, ipout, lsc, ocomb,
                                          Wo, Wao, Wsl, Wsl + WSZ);
    cvt3_kernel<<<dim3(1024, 2), 256, 0, stream>>>(Wo, Wao, Wao, Wsl, Wsl + WSZ, Wsl + 2 * WSZ, (int)WSZ);
  }

  // output projections -> d_out f32 (weights in slots 0,1 either path)
  float* out_img = (float*)d_out;
  float* out_enc = (float*)d_out + (size_t)S_IMG * DM;
  gemm_out_kernel<<<480, 256, 0, stream>>>(ocomb, Wsl, Wsl + WSZ, bo, bao, out_img, out_enc);
}